// Round 1
// baseline (228.791 us; speedup 1.0000x reference)
//
#include <hip/hip_runtime.h>
#include <math.h>

typedef unsigned short u16;
typedef __attribute__((ext_vector_type(8))) short bf16x8;
typedef __attribute__((ext_vector_type(4))) float f32x4;

#define D_EMB 1152
#define NFR 4096
#define SQRT_D 33.94112549695428f

__device__ __forceinline__ u16 f2bf(float f) {
  unsigned u = __float_as_uint(f);
  u = (u + 0x7FFFu + ((u >> 16) & 1u)) >> 16;
  return (u16)u;
}
__device__ __forceinline__ float bf2f(u16 h) { return __uint_as_float(((unsigned)h) << 16); }

__device__ __forceinline__ void gload16(const void* g, void* l) {
  __builtin_amdgcn_global_load_lds((const __attribute__((address_space(1))) void*)g,
                                   (__attribute__((address_space(3))) void*)l, 16, 0, 0);
}

// ---------------- row l2-normalize (D=1152) -> bf16 ----------------
__global__ __launch_bounds__(256) void k_norm_rows(const float* __restrict__ X,
                                                   u16* __restrict__ Y, float eps) {
  const int row = blockIdx.x;
  const float* x = X + (size_t)row * D_EMB;
  const int t = threadIdx.x;
  float ss = 0.f;
#pragma unroll
  for (int i = 0; i < 2; ++i) {
    int idx = t + i * 256;
    if (idx < 288) {
      float4 v = ((const float4*)x)[idx];
      ss += v.x * v.x + v.y * v.y + v.z * v.z + v.w * v.w;
    }
  }
#pragma unroll
  for (int off = 32; off; off >>= 1) ss += __shfl_down(ss, off);
  __shared__ float wsum[4];
  if ((t & 63) == 0) wsum[t >> 6] = ss;
  __syncthreads();
  float inv = 1.f / (sqrtf(wsum[0] + wsum[1] + wsum[2] + wsum[3]) + eps);
#pragma unroll
  for (int i = 0; i < 2; ++i) {
    int idx = t + i * 256;
    if (idx < 288) {
      float4 v = ((const float4*)x)[idx];
      u16 a = f2bf(v.x * inv), b = f2bf(v.y * inv), c = f2bf(v.z * inv), d = f2bf(v.w * inv);
      uint2 pk;
      pk.x = (unsigned)a | ((unsigned)b << 16);
      pk.y = (unsigned)c | ((unsigned)d << 16);
      *(uint2*)(Y + (size_t)row * D_EMB + idx * 4) = pk;
    }
  }
}

// ---------------- transpose fe (4096x1152 f32) -> feT (1152x4096 bf16) ----------------
__global__ void k_transpose_bf16(const float* __restrict__ X, u16* __restrict__ XT) {
  __shared__ float tile[32][33];
  const int k0 = blockIdx.x * 32;
  const int d0 = blockIdx.y * 32;
  const int tx = threadIdx.x, ty = threadIdx.y;
#pragma unroll
  for (int i = ty; i < 32; i += 8)
    tile[i][tx] = X[(size_t)(k0 + i) * D_EMB + d0 + tx];
  __syncthreads();
#pragma unroll
  for (int i = ty; i < 32; i += 8)
    XT[(size_t)(d0 + i) * NFR + k0 + tx] = f2bf(tile[tx][i]);
}

// ---------------- local fusion: per clip of 8 frames ----------------
__global__ __launch_bounds__(256) void k_local(const float* __restrict__ fe,
                                               u16* __restrict__ loc_n,
                                               const float* __restrict__ tau_lp) {
  __shared__ __align__(16) float clip[8][1160];
  __shared__ float norms[8];
  __shared__ float sc[8][8];
  __shared__ float nrm2[8];
  const int c = blockIdx.x;
  const int t = threadIdx.x;
  const float* src = fe + (size_t)c * 8 * D_EMB;
  for (int i = t; i < 2304; i += 256) {
    int r = i / 288, qd = i - r * 288;
    float4 v = ((const float4*)(src + r * D_EMB))[qd];
    *(float4*)&clip[r][qd * 4] = v;
  }
  __syncthreads();
  {
    int r = t >> 5, l32 = t & 31;
    float ss = 0;
    for (int d = l32; d < D_EMB; d += 32) { float v = clip[r][d]; ss += v * v; }
#pragma unroll
    for (int off = 16; off; off >>= 1) ss += __shfl_xor(ss, off);
    if (l32 == 0) norms[r] = sqrtf(ss) + 1e-6f;
  }
  __syncthreads();
  {
    int p = t >> 2, sub = t & 3;
    int i = p >> 3, j = p & 7;
    float s = 0;
    for (int d = sub; d < D_EMB; d += 4) s += clip[i][d] * clip[j][d];
    s += __shfl_xor(s, 1);
    s += __shfl_xor(s, 2);
    if (sub == 0) sc[i][j] = s / (norms[i] * norms[j]);
  }
  __syncthreads();
  const float inv_tls = 1.f / (__expf(tau_lp[0]) * SQRT_D);
  if (t < 64) {
    int i = t >> 3, j = t & 7;
    float v = sc[i][j] * inv_tls;
    float mx = v;
#pragma unroll
    for (int off = 1; off < 8; off <<= 1) mx = fmaxf(mx, __shfl_xor(mx, off));
    float e = __expf(v - mx);
    float s = e;
#pragma unroll
    for (int off = 1; off < 8; off <<= 1) s += __shfl_xor(s, off);
    sc[i][j] = e / s;
  }
  __syncthreads();
  {
    int r = t >> 5, l32 = t & 31;
    float w[8];
#pragma unroll
    for (int j = 0; j < 8; ++j) w[j] = sc[r][j];
    float accv[36];
    float rs = 0;
#pragma unroll
    for (int kk = 0; kk < 36; ++kk) {
      int d = l32 + kk * 32;
      float a = 0;
#pragma unroll
      for (int j = 0; j < 8; ++j) a += w[j] * clip[j][d];
      accv[kk] = a;
      rs += a * a;
    }
#pragma unroll
    for (int off = 16; off; off >>= 1) rs += __shfl_xor(rs, off);
    if (l32 == 0) nrm2[r] = rs;
    __syncthreads();
    float invn = 1.f / sqrtf(nrm2[r]);
#pragma unroll
    for (int kk = 0; kk < 36; ++kk) {
      int d = l32 + kk * 32;
      loc_n[(size_t)(c * 8 + r) * D_EMB + d] = f2bf(accv[kk] * invn);
    }
  }
}

// ---------------- GEMM1: P = exp((nf . nf^T) * inv) , bf16 out ----------------
// m97 structure: 128x128 tile, BK=32, 4 waves (2x2 of 64x64), global_load_lds w=16
__global__ __launch_bounds__(256) void k_gemm_sexp(const u16* __restrict__ A,
                                                   u16* __restrict__ P,
                                                   const float* __restrict__ tau_gp) {
  __shared__ __align__(16) u16 As[128 * 32];
  __shared__ __align__(16) u16 Bs[128 * 32];
  const int tid = threadIdx.x;
  const int lane = tid & 63;
  const int wave = tid >> 6;
  const int wr = (wave >> 1) * 64, wc = (wave & 1) * 64;
  const int row0 = blockIdx.x * 128, col0 = blockIdx.y * 128;
  const int srow = tid >> 2;
  const int scol = (tid & 3) * 8;
  const int fr = lane & 15;
  const int fk = (lane >> 4) * 8;
  f32x4 acc[4][4] = {};

  for (int k0 = 0; k0 < D_EMB; k0 += 32) {
    gload16(A + (size_t)(row0 + srow) * D_EMB + k0 + scol, As + srow * 32 + scol);
    gload16(A + (size_t)(row0 + 64 + srow) * D_EMB + k0 + scol, As + (64 + srow) * 32 + scol);
    gload16(A + (size_t)(col0 + srow) * D_EMB + k0 + scol, Bs + srow * 32 + scol);
    gload16(A + (size_t)(col0 + 64 + srow) * D_EMB + k0 + scol, Bs + (64 + srow) * 32 + scol);
    __syncthreads();
    bf16x8 af[4], bfr[4];
#pragma unroll
    for (int m = 0; m < 4; ++m) af[m] = *(const bf16x8*)&As[(wr + m * 16 + fr) * 32 + fk];
#pragma unroll
    for (int n = 0; n < 4; ++n) bfr[n] = *(const bf16x8*)&Bs[(wc + n * 16 + fr) * 32 + fk];
#pragma unroll
    for (int m = 0; m < 4; ++m)
#pragma unroll
      for (int n = 0; n < 4; ++n)
        acc[m][n] = __builtin_amdgcn_mfma_f32_16x16x32_bf16(af[m], bfr[n], acc[m][n], 0, 0, 0);
    __syncthreads();
  }
  const float inv = 1.f / (__expf(tau_gp[0]) * SQRT_D);
#pragma unroll
  for (int m = 0; m < 4; ++m) {
#pragma unroll
    for (int n = 0; n < 4; ++n) {
      int col = col0 + wc + n * 16 + fr;
#pragma unroll
      for (int r = 0; r < 4; ++r) {
        int row = row0 + wr + m * 16 + (lane >> 4) * 4 + r;
        P[(size_t)row * NFR + col] = f2bf(__expf(acc[m][n][r] * inv));
      }
    }
  }
}

// ---------------- GEMM2: O = P (4096x4096) . feT^T (feT: 1152x4096), f32 out ----------------
__global__ __launch_bounds__(256) void k_gemm_o(const u16* __restrict__ A,
                                                const u16* __restrict__ B,
                                                float* __restrict__ O) {
  __shared__ __align__(16) u16 As[128 * 32];
  __shared__ __align__(16) u16 Bs[128 * 32];
  const int tid = threadIdx.x;
  const int lane = tid & 63;
  const int wave = tid >> 6;
  const int wr = (wave >> 1) * 64, wc = (wave & 1) * 64;
  const int row0 = blockIdx.x * 128, col0 = blockIdx.y * 128;
  const int srow = tid >> 2;
  const int scol = (tid & 3) * 8;
  const int fr = lane & 15;
  const int fk = (lane >> 4) * 8;
  f32x4 acc[4][4] = {};

  for (int k0 = 0; k0 < NFR; k0 += 32) {
    gload16(A + (size_t)(row0 + srow) * NFR + k0 + scol, As + srow * 32 + scol);
    gload16(A + (size_t)(row0 + 64 + srow) * NFR + k0 + scol, As + (64 + srow) * 32 + scol);
    gload16(B + (size_t)(col0 + srow) * NFR + k0 + scol, Bs + srow * 32 + scol);
    gload16(B + (size_t)(col0 + 64 + srow) * NFR + k0 + scol, Bs + (64 + srow) * 32 + scol);
    __syncthreads();
    bf16x8 af[4], bfr[4];
#pragma unroll
    for (int m = 0; m < 4; ++m) af[m] = *(const bf16x8*)&As[(wr + m * 16 + fr) * 32 + fk];
#pragma unroll
    for (int n = 0; n < 4; ++n) bfr[n] = *(const bf16x8*)&Bs[(wc + n * 16 + fr) * 32 + fk];
#pragma unroll
    for (int m = 0; m < 4; ++m)
#pragma unroll
      for (int n = 0; n < 4; ++n)
        acc[m][n] = __builtin_amdgcn_mfma_f32_16x16x32_bf16(af[m], bfr[n], acc[m][n], 0, 0, 0);
    __syncthreads();
  }
#pragma unroll
  for (int m = 0; m < 4; ++m) {
#pragma unroll
    for (int n = 0; n < 4; ++n) {
      int col = col0 + wc + n * 16 + fr;
#pragma unroll
      for (int r = 0; r < 4; ++r) {
        int row = row0 + wr + m * 16 + (lane >> 4) * 4 + r;
        O[(size_t)row * D_EMB + col] = acc[m][n][r];
      }
    }
  }
}

// ---------------- te scores + fuse + max over queries -> logits[4096] ----------------
#define ACC8(dst, r, tp)                                                            \
  dst += bf2f(tp[0]) * bf2f((u16)(r.x & 0xffff)) + bf2f(tp[1]) * bf2f((u16)(r.x >> 16)) + \
         bf2f(tp[2]) * bf2f((u16)(r.y & 0xffff)) + bf2f(tp[3]) * bf2f((u16)(r.y >> 16)) + \
         bf2f(tp[4]) * bf2f((u16)(r.z & 0xffff)) + bf2f(tp[5]) * bf2f((u16)(r.z >> 16)) + \
         bf2f(tp[6]) * bf2f((u16)(r.w & 0xffff)) + bf2f(tp[7]) * bf2f((u16)(r.w >> 16));

__global__ __launch_bounds__(256) void k_score_max(const u16* __restrict__ te_n,
                                                   const u16* __restrict__ nf,
                                                   const u16* __restrict__ loc_n,
                                                   const u16* __restrict__ glob_n,
                                                   float* __restrict__ logits,
                                                   const float* __restrict__ lsp,
                                                   const float* __restrict__ lbp) {
  __shared__ u16 te16[16][1160];
  const int t = threadIdx.x;
  for (int idx = t; idx < 16 * D_EMB; idx += 256) {
    int q = idx / D_EMB, d = idx - q * D_EMB;
    te16[q][d] = te_n[idx];
  }
  __syncthreads();
  const int q = t & 15;
  const int fl = t >> 4;
  const int frame = blockIdx.x * 16 + fl;
  const uint4* an = (const uint4*)(nf + (size_t)frame * D_EMB);
  const uint4* al = (const uint4*)(loc_n + (size_t)frame * D_EMB);
  const uint4* ag = (const uint4*)(glob_n + (size_t)frame * D_EMB);
  float d0 = 0, d1 = 0, d2 = 0;
  const u16* tq = te16[q];
  for (int ch = 0; ch < 144; ++ch) {
    uint4 ra = an[ch], rb = al[ch], rc = ag[ch];
    const u16* tp = tq + ch * 8;
    ACC8(d0, ra, tp)
    ACC8(d1, rb, tp)
    ACC8(d2, rc, tp)
  }
  float fused = __expf(lsp[0]) * (0.9f * d0 + 0.05f * d1 + 0.05f * d2) + lbp[0];
#pragma unroll
  for (int off = 1; off < 16; off <<= 1) fused = fmaxf(fused, __shfl_xor(fused, off));
  if (q == 0) logits[frame] = fused;
}

// ---------------- softmax-pool per clip + loss ----------------
__global__ __launch_bounds__(512) void k_final(const float* __restrict__ logits,
                                               const float* __restrict__ labels,
                                               float* __restrict__ out) {
  const int t = threadIdx.x;
  float x[8];
  float m = -1e30f;
#pragma unroll
  for (int j = 0; j < 8; ++j) { x[j] = logits[t * 8 + j]; m = fmaxf(m, x[j]); }
  float se = 0, swx = 0;
#pragma unroll
  for (int j = 0; j < 8; ++j) { float e = __expf(x[j] - m); se += e; swx += e * x[j]; }
  float pooled = swx / se;
  out[1 + t] = pooled;
  float lab = labels[t * 8];
  __shared__ float red[8];
  float v = lab;
#pragma unroll
  for (int off = 32; off; off >>= 1) v += __shfl_down(v, off);
  if ((t & 63) == 0) red[t >> 6] = v;
  __syncthreads();
  float total = 0;
#pragma unroll
  for (int w = 0; w < 8; ++w) total += red[w];
  float mean = total * (1.f / 512.f);
  float wgt = pooled * (lab - mean);
  float lsg = (wgt >= 0.f) ? -log1pf(__expf(-wgt)) : (wgt - log1pf(__expf(wgt)));
  __syncthreads();
  float v2 = lsg;
#pragma unroll
  for (int off = 32; off; off >>= 1) v2 += __shfl_down(v2, off);
  if ((t & 63) == 0) red[t >> 6] = v2;
  __syncthreads();
  if (t == 0) {
    float tl = 0;
#pragma unroll
    for (int w = 0; w < 8; ++w) tl += red[w];
    out[0] = -tl;
  }
}

extern "C" void kernel_launch(void* const* d_in, const int* in_sizes, int n_in,
                              void* d_out, int out_size, void* d_ws, size_t ws_size,
                              hipStream_t stream) {
  const float* fe = (const float*)d_in[0];
  const float* text = (const float*)d_in[1];
  const float* labels = (const float*)d_in[2];
  const float* tau_lp = (const float*)d_in[3];
  const float* tau_gp = (const float*)d_in[4];
  const float* lsp = (const float*)d_in[5];
  const float* lbp = (const float*)d_in[6];
  float* out = (float*)d_out;
  char* ws = (char*)d_ws;

  // ws layout (bytes): all 256-aligned; total ~90.2 MB
  u16* nf = (u16*)(ws + 0);              // 4096x1152 bf16 (l2norm eps=1e-6; also serves fe_n)
  u16* feT = (u16*)(ws + 9437184);       // 1152x4096 bf16
  u16* loc_n = (u16*)(ws + 18874368);    // 4096x1152 bf16
  u16* glob_n = (u16*)(ws + 28311552);   // 4096x1152 bf16
  u16* te_n = (u16*)(ws + 37748736);     // 16x1152 bf16
  float* logits = (float*)(ws + 37785600);  // 4096 f32
  float* O = (float*)(ws + 37801984);    // 4096x1152 f32
  u16* P = (u16*)(ws + 56676352);        // 4096x4096 bf16 = exp(S)

  hipLaunchKernelGGL(k_norm_rows, dim3(4096), dim3(256), 0, stream, fe, nf, 1e-6f);
  hipLaunchKernelGGL(k_norm_rows, dim3(16), dim3(256), 0, stream, text, te_n, 0.f);
  hipLaunchKernelGGL(k_transpose_bf16, dim3(128, 36), dim3(32, 8), 0, stream, fe, feT);
  hipLaunchKernelGGL(k_local, dim3(512), dim3(256), 0, stream, fe, loc_n, tau_lp);
  hipLaunchKernelGGL(k_gemm_sexp, dim3(32, 32), dim3(256), 0, stream, nf, P, tau_gp);
  hipLaunchKernelGGL(k_gemm_o, dim3(32, 9), dim3(256), 0, stream, P, feT, O);
  hipLaunchKernelGGL(k_norm_rows, dim3(4096), dim3(256), 0, stream, O, glob_n, 0.f);
  hipLaunchKernelGGL(k_score_max, dim3(256), dim3(256), 0, stream, te_n, nf, loc_n, glob_n,
                     logits, lsp, lbp);
  hipLaunchKernelGGL(k_final, dim3(1), dim3(512), 0, stream, logits, labels, out);
}

// Round 2
// 207.075 us; speedup vs baseline: 1.1049x; 1.1049x over previous
//
#include <hip/hip_runtime.h>
#include <math.h>

typedef unsigned short u16;
typedef __attribute__((ext_vector_type(8))) short bf16x8;
typedef __attribute__((ext_vector_type(4))) float f32x4;

#define D_EMB 1152
#define NFR 4096
#define SQRT_D 33.94112549695428f

__device__ __forceinline__ u16 f2bf(float f) {
  unsigned u = __float_as_uint(f);
  u = (u + 0x7FFFu + ((u >> 16) & 1u)) >> 16;
  return (u16)u;
}
__device__ __forceinline__ float bf2f(u16 h) { return __uint_as_float(((unsigned)h) << 16); }

__device__ __forceinline__ void gload16(const void* g, void* l) {
  __builtin_amdgcn_global_load_lds((const __attribute__((address_space(1))) void*)g,
                                   (__attribute__((address_space(3))) void*)l, 16, 0, 0);
}

// ---------------- row l2-normalize (D=1152) -> bf16 ----------------
__global__ __launch_bounds__(256) void k_norm_rows(const float* __restrict__ X,
                                                   u16* __restrict__ Y, float eps) {
  const int row = blockIdx.x;
  const float* x = X + (size_t)row * D_EMB;
  const int t = threadIdx.x;
  float4 vv[2];
  float ss = 0.f;
#pragma unroll
  for (int i = 0; i < 2; ++i) {
    int idx = t + i * 256;
    if (idx < 288) {
      float4 v = ((const float4*)x)[idx];
      vv[i] = v;
      ss += v.x * v.x + v.y * v.y + v.z * v.z + v.w * v.w;
    }
  }
#pragma unroll
  for (int off = 32; off; off >>= 1) ss += __shfl_down(ss, off);
  __shared__ float wsum[4];
  if ((t & 63) == 0) wsum[t >> 6] = ss;
  __syncthreads();
  float inv = 1.f / (sqrtf(wsum[0] + wsum[1] + wsum[2] + wsum[3]) + eps);
#pragma unroll
  for (int i = 0; i < 2; ++i) {
    int idx = t + i * 256;
    if (idx < 288) {
      float4 v = vv[i];
      u16 a = f2bf(v.x * inv), b = f2bf(v.y * inv), c = f2bf(v.z * inv), d = f2bf(v.w * inv);
      uint2 pk;
      pk.x = (unsigned)a | ((unsigned)b << 16);
      pk.y = (unsigned)c | ((unsigned)d << 16);
      *(uint2*)(Y + (size_t)row * D_EMB + idx * 4) = pk;
    }
  }
}

// ---------------- sum nsplit partials + row l2-normalize -> bf16 ----------------
__global__ __launch_bounds__(256) void k_norm_sum(const float* __restrict__ Xp,
                                                  u16* __restrict__ Y, int nsplit) {
  const int row = blockIdx.x;
  const int t = threadIdx.x;
  float4 vv[2];
  float ss = 0.f;
#pragma unroll
  for (int i = 0; i < 2; ++i) {
    int idx = t + i * 256;
    if (idx < 288) {
      float4 a = ((const float4*)(Xp + (size_t)row * D_EMB))[idx];
      for (int p = 1; p < nsplit; ++p) {
        float4 v = ((const float4*)(Xp + (size_t)p * NFR * D_EMB + (size_t)row * D_EMB))[idx];
        a.x += v.x; a.y += v.y; a.z += v.z; a.w += v.w;
      }
      vv[i] = a;
      ss += a.x * a.x + a.y * a.y + a.z * a.z + a.w * a.w;
    }
  }
#pragma unroll
  for (int off = 32; off; off >>= 1) ss += __shfl_down(ss, off);
  __shared__ float wsum[4];
  if ((t & 63) == 0) wsum[t >> 6] = ss;
  __syncthreads();
  float inv = 1.f / sqrtf(wsum[0] + wsum[1] + wsum[2] + wsum[3]);
#pragma unroll
  for (int i = 0; i < 2; ++i) {
    int idx = t + i * 256;
    if (idx < 288) {
      float4 v = vv[i];
      u16 a = f2bf(v.x * inv), b = f2bf(v.y * inv), c = f2bf(v.z * inv), d = f2bf(v.w * inv);
      uint2 pk;
      pk.x = (unsigned)a | ((unsigned)b << 16);
      pk.y = (unsigned)c | ((unsigned)d << 16);
      *(uint2*)(Y + (size_t)row * D_EMB + idx * 4) = pk;
    }
  }
}

// ---------------- transpose fe (4096x1152 f32) -> feT (1152x4096 bf16) ----------------
__global__ void k_transpose_bf16(const float* __restrict__ X, u16* __restrict__ XT) {
  __shared__ float tile[32][33];
  const int k0 = blockIdx.x * 32;
  const int d0 = blockIdx.y * 32;
  const int tx = threadIdx.x, ty = threadIdx.y;
#pragma unroll
  for (int i = ty; i < 32; i += 8)
    tile[i][tx] = X[(size_t)(k0 + i) * D_EMB + d0 + tx];
  __syncthreads();
#pragma unroll
  for (int i = ty; i < 32; i += 8)
    XT[(size_t)(d0 + i) * NFR + k0 + tx] = f2bf(tile[tx][i]);
}

// ---------------- local fusion: per clip of 8 frames ----------------
__global__ __launch_bounds__(256) void k_local(const float* __restrict__ fe,
                                               u16* __restrict__ loc_n,
                                               const float* __restrict__ tau_lp) {
  __shared__ __align__(16) float clip[8][1160];
  __shared__ float norms[8];
  __shared__ float sc[8][8];
  __shared__ float nrm2[8];
  const int c = blockIdx.x;
  const int t = threadIdx.x;
  const float* src = fe + (size_t)c * 8 * D_EMB;
  for (int i = t; i < 2304; i += 256) {
    int r = i / 288, qd = i - r * 288;
    float4 v = ((const float4*)(src + r * D_EMB))[qd];
    *(float4*)&clip[r][qd * 4] = v;
  }
  __syncthreads();
  {
    int r = t >> 5, l32 = t & 31;
    float ss = 0;
    for (int d = l32; d < D_EMB; d += 32) { float v = clip[r][d]; ss += v * v; }
#pragma unroll
    for (int off = 16; off; off >>= 1) ss += __shfl_xor(ss, off);
    if (l32 == 0) norms[r] = sqrtf(ss) + 1e-6f;
  }
  __syncthreads();
  {
    int p = t >> 2, sub = t & 3;
    int i = p >> 3, j = p & 7;
    float s = 0;
    for (int d = sub; d < D_EMB; d += 4) s += clip[i][d] * clip[j][d];
    s += __shfl_xor(s, 1);
    s += __shfl_xor(s, 2);
    if (sub == 0) sc[i][j] = s / (norms[i] * norms[j]);
  }
  __syncthreads();
  const float inv_tls = 1.f / (__expf(tau_lp[0]) * SQRT_D);
  if (t < 64) {
    int i = t >> 3, j = t & 7;
    float v = sc[i][j] * inv_tls;
    float mx = v;
#pragma unroll
    for (int off = 1; off < 8; off <<= 1) mx = fmaxf(mx, __shfl_xor(mx, off));
    float e = __expf(v - mx);
    float s = e;
#pragma unroll
    for (int off = 1; off < 8; off <<= 1) s += __shfl_xor(s, off);
    sc[i][j] = e / s;
  }
  __syncthreads();
  {
    int r = t >> 5, l32 = t & 31;
    float w[8];
#pragma unroll
    for (int j = 0; j < 8; ++j) w[j] = sc[r][j];
    float accv[36];
    float rs = 0;
#pragma unroll
    for (int kk = 0; kk < 36; ++kk) {
      int d = l32 + kk * 32;
      float a = 0;
#pragma unroll
      for (int j = 0; j < 8; ++j) a += w[j] * clip[j][d];
      accv[kk] = a;
      rs += a * a;
    }
#pragma unroll
    for (int off = 16; off; off >>= 1) rs += __shfl_xor(rs, off);
    if (l32 == 0) nrm2[r] = rs;
    __syncthreads();
    float invn = 1.f / sqrtf(nrm2[r]);
#pragma unroll
    for (int kk = 0; kk < 36; ++kk) {
      int d = l32 + kk * 32;
      loc_n[(size_t)(c * 8 + r) * D_EMB + d] = f2bf(accv[kk] * invn);
    }
  }
}

// ---------------- GEMM1: P = exp((nf . nf^T) * inv) , bf16 out ----------------
// m97 structure: 128x128 tile, BK=32, 4 waves (2x2 of 64x64), global_load_lds w=16
__global__ __launch_bounds__(256) void k_gemm_sexp(const u16* __restrict__ A,
                                                   u16* __restrict__ P,
                                                   const float* __restrict__ tau_gp) {
  __shared__ __align__(16) u16 As[128 * 32];
  __shared__ __align__(16) u16 Bs[128 * 32];
  const int tid = threadIdx.x;
  const int lane = tid & 63;
  const int wave = tid >> 6;
  const int wr = (wave >> 1) * 64, wc = (wave & 1) * 64;
  const int row0 = blockIdx.x * 128, col0 = blockIdx.y * 128;
  const int srow = tid >> 2;
  const int scol = (tid & 3) * 8;
  const int fr = lane & 15;
  const int fk = (lane >> 4) * 8;
  f32x4 acc[4][4] = {};

  for (int k0 = 0; k0 < D_EMB; k0 += 32) {
    gload16(A + (size_t)(row0 + srow) * D_EMB + k0 + scol, As + srow * 32 + scol);
    gload16(A + (size_t)(row0 + 64 + srow) * D_EMB + k0 + scol, As + (64 + srow) * 32 + scol);
    gload16(A + (size_t)(col0 + srow) * D_EMB + k0 + scol, Bs + srow * 32 + scol);
    gload16(A + (size_t)(col0 + 64 + srow) * D_EMB + k0 + scol, Bs + (64 + srow) * 32 + scol);
    __syncthreads();
    bf16x8 af[4], bfr[4];
#pragma unroll
    for (int m = 0; m < 4; ++m) af[m] = *(const bf16x8*)&As[(wr + m * 16 + fr) * 32 + fk];
#pragma unroll
    for (int n = 0; n < 4; ++n) bfr[n] = *(const bf16x8*)&Bs[(wc + n * 16 + fr) * 32 + fk];
#pragma unroll
    for (int m = 0; m < 4; ++m)
#pragma unroll
      for (int n = 0; n < 4; ++n)
        acc[m][n] = __builtin_amdgcn_mfma_f32_16x16x32_bf16(af[m], bfr[n], acc[m][n], 0, 0, 0);
    __syncthreads();
  }
  const float inv = 1.f / (__expf(tau_gp[0]) * SQRT_D);
#pragma unroll
  for (int m = 0; m < 4; ++m) {
#pragma unroll
    for (int n = 0; n < 4; ++n) {
      int col = col0 + wc + n * 16 + fr;
#pragma unroll
      for (int r = 0; r < 4; ++r) {
        int row = row0 + wr + m * 16 + (lane >> 4) * 4 + r;
        P[(size_t)row * NFR + col] = f2bf(__expf(acc[m][n][r] * inv));
      }
    }
  }
}

// ---------------- GEMM2 (split-K): Opart[z] = P[:, zK:(z+1)K] . fe[zK:(z+1)K, :] ----------------
__global__ __launch_bounds__(256) void k_gemm_o(const u16* __restrict__ A,
                                                const u16* __restrict__ B,
                                                float* __restrict__ Opart, int klen) {
  __shared__ __align__(16) u16 As[128 * 32];
  __shared__ __align__(16) u16 Bs[128 * 32];
  const int tid = threadIdx.x;
  const int lane = tid & 63;
  const int wave = tid >> 6;
  const int wr = (wave >> 1) * 64, wc = (wave & 1) * 64;
  const int row0 = blockIdx.x * 128, col0 = blockIdx.y * 128;
  const int kbase = blockIdx.z * klen;
  float* __restrict__ O = Opart + (size_t)blockIdx.z * NFR * D_EMB;
  const int srow = tid >> 2;
  const int scol = (tid & 3) * 8;
  const int fr = lane & 15;
  const int fk = (lane >> 4) * 8;
  f32x4 acc[4][4] = {};

  for (int k0 = kbase; k0 < kbase + klen; k0 += 32) {
    gload16(A + (size_t)(row0 + srow) * NFR + k0 + scol, As + srow * 32 + scol);
    gload16(A + (size_t)(row0 + 64 + srow) * NFR + k0 + scol, As + (64 + srow) * 32 + scol);
    gload16(B + (size_t)(col0 + srow) * NFR + k0 + scol, Bs + srow * 32 + scol);
    gload16(B + (size_t)(col0 + 64 + srow) * NFR + k0 + scol, Bs + (64 + srow) * 32 + scol);
    __syncthreads();
    bf16x8 af[4], bfr[4];
#pragma unroll
    for (int m = 0; m < 4; ++m) af[m] = *(const bf16x8*)&As[(wr + m * 16 + fr) * 32 + fk];
#pragma unroll
    for (int n = 0; n < 4; ++n) bfr[n] = *(const bf16x8*)&Bs[(wc + n * 16 + fr) * 32 + fk];
#pragma unroll
    for (int m = 0; m < 4; ++m)
#pragma unroll
      for (int n = 0; n < 4; ++n)
        acc[m][n] = __builtin_amdgcn_mfma_f32_16x16x32_bf16(af[m], bfr[n], acc[m][n], 0, 0, 0);
    __syncthreads();
  }
#pragma unroll
  for (int m = 0; m < 4; ++m) {
#pragma unroll
    for (int n = 0; n < 4; ++n) {
      int col = col0 + wc + n * 16 + fr;
#pragma unroll
      for (int r = 0; r < 4; ++r) {
        int row = row0 + wr + m * 16 + (lane >> 4) * 4 + r;
        O[(size_t)row * D_EMB + col] = acc[m][n][r];
      }
    }
  }
}

// ---------------- te scores + fuse + max over queries -> logits[4096] ----------------
#define ACC8(dst, r, tp)                                                            \
  dst += bf2f(tp[0]) * bf2f((u16)(r.x & 0xffff)) + bf2f(tp[1]) * bf2f((u16)(r.x >> 16)) + \
         bf2f(tp[2]) * bf2f((u16)(r.y & 0xffff)) + bf2f(tp[3]) * bf2f((u16)(r.y >> 16)) + \
         bf2f(tp[4]) * bf2f((u16)(r.z & 0xffff)) + bf2f(tp[5]) * bf2f((u16)(r.z >> 16)) + \
         bf2f(tp[6]) * bf2f((u16)(r.w & 0xffff)) + bf2f(tp[7]) * bf2f((u16)(r.w >> 16));

__global__ __launch_bounds__(256) void k_score_max(const u16* __restrict__ te_n,
                                                   const u16* __restrict__ nf,
                                                   const u16* __restrict__ loc_n,
                                                   const u16* __restrict__ glob_n,
                                                   float* __restrict__ logits,
                                                   const float* __restrict__ lsp,
                                                   const float* __restrict__ lbp) {
  __shared__ u16 te16[16][1160];
  const int t = threadIdx.x;
  for (int idx = t; idx < 16 * D_EMB; idx += 256) {
    int q = idx / D_EMB, d = idx - q * D_EMB;
    te16[q][d] = te_n[idx];
  }
  __syncthreads();
  const int q = t & 15;
  const int fl = t >> 4;
  const int frame = blockIdx.x * 16 + fl;
  const uint4* an = (const uint4*)(nf + (size_t)frame * D_EMB);
  const uint4* al = (const uint4*)(loc_n + (size_t)frame * D_EMB);
  const uint4* ag = (const uint4*)(glob_n + (size_t)frame * D_EMB);
  float d0 = 0, d1 = 0, d2 = 0;
  const u16* tq = te16[q];
  for (int ch = 0; ch < 144; ++ch) {
    uint4 ra = an[ch], rb = al[ch], rc = ag[ch];
    const u16* tp = tq + ch * 8;
    ACC8(d0, ra, tp)
    ACC8(d1, rb, tp)
    ACC8(d2, rc, tp)
  }
  float fused = __expf(lsp[0]) * (0.9f * d0 + 0.05f * d1 + 0.05f * d2) + lbp[0];
#pragma unroll
  for (int off = 1; off < 16; off <<= 1) fused = fmaxf(fused, __shfl_xor(fused, off));
  if (q == 0) logits[frame] = fused;
}

// ---------------- softmax-pool per clip + loss ----------------
__global__ __launch_bounds__(512) void k_final(const float* __restrict__ logits,
                                               const float* __restrict__ labels,
                                               float* __restrict__ out) {
  const int t = threadIdx.x;
  float x[8];
  float m = -1e30f;
#pragma unroll
  for (int j = 0; j < 8; ++j) { x[j] = logits[t * 8 + j]; m = fmaxf(m, x[j]); }
  float se = 0, swx = 0;
#pragma unroll
  for (int j = 0; j < 8; ++j) { float e = __expf(x[j] - m); se += e; swx += e * x[j]; }
  float pooled = swx / se;
  out[1 + t] = pooled;
  float lab = labels[t * 8];
  __shared__ float red[8];
  float v = lab;
#pragma unroll
  for (int off = 32; off; off >>= 1) v += __shfl_down(v, off);
  if ((t & 63) == 0) red[t >> 6] = v;
  __syncthreads();
  float total = 0;
#pragma unroll
  for (int w = 0; w < 8; ++w) total += red[w];
  float mean = total * (1.f / 512.f);
  float wgt = pooled * (lab - mean);
  float lsg = (wgt >= 0.f) ? -log1pf(__expf(-wgt)) : (wgt - log1pf(__expf(wgt)));
  __syncthreads();
  float v2 = lsg;
#pragma unroll
  for (int off = 32; off; off >>= 1) v2 += __shfl_down(v2, off);
  if ((t & 63) == 0) red[t >> 6] = v2;
  __syncthreads();
  if (t == 0) {
    float tl = 0;
#pragma unroll
    for (int w = 0; w < 8; ++w) tl += red[w];
    out[0] = -tl;
  }
}

extern "C" void kernel_launch(void* const* d_in, const int* in_sizes, int n_in,
                              void* d_out, int out_size, void* d_ws, size_t ws_size,
                              hipStream_t stream) {
  const float* fe = (const float*)d_in[0];
  const float* text = (const float*)d_in[1];
  const float* labels = (const float*)d_in[2];
  const float* tau_lp = (const float*)d_in[3];
  const float* tau_gp = (const float*)d_in[4];
  const float* lsp = (const float*)d_in[5];
  const float* lbp = (const float*)d_in[6];
  float* out = (float*)d_out;
  char* ws = (char*)d_ws;

  // ws layout (bytes), all 256-aligned:
  u16* nf = (u16*)(ws + 0);                 // 4096x1152 bf16
  u16* feT = (u16*)(ws + 9437184);          // 1152x4096 bf16
  u16* loc_n = (u16*)(ws + 18874368);       // 4096x1152 bf16
  u16* glob_n = (u16*)(ws + 28311552);      // 4096x1152 bf16
  u16* te_n = (u16*)(ws + 37748736);        // 16x1152 bf16
  float* logits = (float*)(ws + 37785600);  // 4096 f32
  u16* P = (u16*)(ws + 37801984);           // 4096x4096 bf16 = exp(S')
  const size_t part_off = 71356416ull;      // split-K partials, f32, nsplit x 4096x1152
  float* Opart = (float*)(ws + part_off);

  const size_t part_sz = (size_t)NFR * D_EMB * 4;  // 18874368
  int nsplit = 1;
  if (ws_size >= part_off + 4 * part_sz) nsplit = 4;
  else if (ws_size >= part_off + 2 * part_sz) nsplit = 2;

  hipLaunchKernelGGL(k_norm_rows, dim3(4096), dim3(256), 0, stream, fe, nf, 1e-6f);
  hipLaunchKernelGGL(k_norm_rows, dim3(16), dim3(256), 0, stream, text, te_n, 0.f);
  hipLaunchKernelGGL(k_transpose_bf16, dim3(128, 36), dim3(32, 8), 0, stream, fe, feT);
  hipLaunchKernelGGL(k_local, dim3(512), dim3(256), 0, stream, fe, loc_n, tau_lp);
  hipLaunchKernelGGL(k_gemm_sexp, dim3(32, 32), dim3(256), 0, stream, nf, P, tau_gp);
  hipLaunchKernelGGL(k_gemm_o, dim3(32, 9, nsplit), dim3(256), 0, stream, P, feT, Opart,
                     NFR / nsplit);
  hipLaunchKernelGGL(k_norm_sum, dim3(4096), dim3(256), 0, stream, Opart, glob_n, nsplit);
  hipLaunchKernelGGL(k_score_max, dim3(256), dim3(256), 0, stream, te_n, nf, loc_n, glob_n,
                     logits, lsp, lbp);
  hipLaunchKernelGGL(k_final, dim3(1), dim3(512), 0, stream, logits, labels, out);
}

// Round 3
// 149.791 us; speedup vs baseline: 1.5274x; 1.3824x over previous
//
#include <hip/hip_runtime.h>
#include <math.h>

typedef unsigned short u16;
typedef __attribute__((ext_vector_type(8))) short bf16x8;
typedef __attribute__((ext_vector_type(4))) float f32x4;

#define D_EMB 1152
#define NFR 4096
#define SQRT_D 33.94112549695428f

__device__ __forceinline__ u16 f2bf(float f) {
  unsigned u = __float_as_uint(f);
  u = (u + 0x7FFFu + ((u >> 16) & 1u)) >> 16;
  return (u16)u;
}
__device__ __forceinline__ float bf2f(u16 h) { return __uint_as_float(((unsigned)h) << 16); }

__device__ __forceinline__ void gload16(const void* g, void* l) {
  __builtin_amdgcn_global_load_lds((const __attribute__((address_space(1))) void*)g,
                                   (__attribute__((address_space(3))) void*)l, 16, 0, 0);
}

// ---------------- row l2-normalize (D=1152) -> bf16, plus 1/(norm+eps) ----------------
__global__ __launch_bounds__(256) void k_norm_rows(const float* __restrict__ X,
                                                   u16* __restrict__ Y,
                                                   float* __restrict__ invout, float eps) {
  const int row = blockIdx.x;
  const float* x = X + (size_t)row * D_EMB;
  const int t = threadIdx.x;
  float4 vv[2];
  float ss = 0.f;
#pragma unroll
  for (int i = 0; i < 2; ++i) {
    int idx = t + i * 256;
    if (idx < 288) {
      float4 v = ((const float4*)x)[idx];
      vv[i] = v;
      ss += v.x * v.x + v.y * v.y + v.z * v.z + v.w * v.w;
    }
  }
#pragma unroll
  for (int off = 32; off; off >>= 1) ss += __shfl_down(ss, off);
  __shared__ float wsum[4];
  if ((t & 63) == 0) wsum[t >> 6] = ss;
  __syncthreads();
  float inv = 1.f / (sqrtf(wsum[0] + wsum[1] + wsum[2] + wsum[3]) + eps);
  if (t == 0) invout[row] = inv;
#pragma unroll
  for (int i = 0; i < 2; ++i) {
    int idx = t + i * 256;
    if (idx < 288) {
      float4 v = vv[i];
      u16 a = f2bf(v.x * inv), b = f2bf(v.y * inv), c = f2bf(v.z * inv), d = f2bf(v.w * inv);
      uint2 pk;
      pk.x = (unsigned)a | ((unsigned)b << 16);
      pk.y = (unsigned)c | ((unsigned)d << 16);
      *(uint2*)(Y + (size_t)row * D_EMB + idx * 4) = pk;
    }
  }
}

// ------- transpose fe (4096x1152 f32) -> feT (1152x4096 bf16) + per-kblock colsum partials -------
__global__ void k_transpose_colsum(const float* __restrict__ X, u16* __restrict__ XT,
                                   float* __restrict__ kpart) {
  __shared__ float tile[32][33];
  __shared__ float cred[8][32];
  const int k0 = blockIdx.x * 32;
  const int d0 = blockIdx.y * 32;
  const int tx = threadIdx.x, ty = threadIdx.y;
  float cs = 0.f;
#pragma unroll
  for (int s = 0; s < 4; ++s) {
    float v = X[(size_t)(k0 + ty + 8 * s) * D_EMB + d0 + tx];
    tile[ty + 8 * s][tx] = v;
    cs += v;
  }
  cred[ty][tx] = cs;
  __syncthreads();
#pragma unroll
  for (int i = ty; i < 32; i += 8)
    XT[(size_t)(d0 + i) * NFR + k0 + tx] = f2bf(tile[tx][i]);
  if (ty == 0) {
    float s = 0.f;
#pragma unroll
    for (int w = 0; w < 8; ++w) s += cred[w][tx];
    kpart[blockIdx.x * D_EMB + d0 + tx] = s;
  }
}

// ---------------- reduce column-sum partials: colsum[d] = sum_kb kpart[kb][d] ----------------
__global__ __launch_bounds__(128) void k_colsum_reduce(const float* __restrict__ kpart,
                                                       float* __restrict__ colsum) {
  const int col = blockIdx.x * 128 + threadIdx.x;
  float s = 0.f;
  for (int kb = 0; kb < 128; ++kb) s += kpart[kb * D_EMB + col];
  colsum[col] = s;
}

// ---------------- nfT[d][k] = feT[d][k] * invr[k] ----------------
__global__ __launch_bounds__(256) void k_scale_cols(const u16* __restrict__ feT,
                                                    const float* __restrict__ invr,
                                                    u16* __restrict__ nfT) {
  const size_t gid = (size_t)blockIdx.x * 256 + threadIdx.x;
  const size_t base = gid * 8;
  const int k = (int)(base & (NFR - 1));
  uint4 v = ((const uint4*)feT)[gid];
  float4 r0 = *(const float4*)(invr + k);
  float4 r1 = *(const float4*)(invr + k + 4);
  unsigned w0 = (unsigned)f2bf(bf2f((u16)(v.x & 0xffff)) * r0.x) |
                ((unsigned)f2bf(bf2f((u16)(v.x >> 16)) * r0.y) << 16);
  unsigned w1 = (unsigned)f2bf(bf2f((u16)(v.y & 0xffff)) * r0.z) |
                ((unsigned)f2bf(bf2f((u16)(v.y >> 16)) * r0.w) << 16);
  unsigned w2 = (unsigned)f2bf(bf2f((u16)(v.z & 0xffff)) * r1.x) |
                ((unsigned)f2bf(bf2f((u16)(v.z >> 16)) * r1.y) << 16);
  unsigned w3 = (unsigned)f2bf(bf2f((u16)(v.w & 0xffff)) * r1.z) |
                ((unsigned)f2bf(bf2f((u16)(v.w >> 16)) * r1.w) << 16);
  uint4 o = {w0, w1, w2, w3};
  ((uint4*)nfT)[gid] = o;
}

// ---------------- local fusion: per clip of 8 frames ----------------
__global__ __launch_bounds__(256) void k_local(const float* __restrict__ fe,
                                               u16* __restrict__ loc_n,
                                               const float* __restrict__ tau_lp) {
  __shared__ __align__(16) float clip[8][1160];
  __shared__ float norms[8];
  __shared__ float sc[8][8];
  __shared__ float nrm2[8];
  const int c = blockIdx.x;
  const int t = threadIdx.x;
  const float* src = fe + (size_t)c * 8 * D_EMB;
  for (int i = t; i < 2304; i += 256) {
    int r = i / 288, qd = i - r * 288;
    float4 v = ((const float4*)(src + r * D_EMB))[qd];
    *(float4*)&clip[r][qd * 4] = v;
  }
  __syncthreads();
  {
    int r = t >> 5, l32 = t & 31;
    float ss = 0;
    for (int d = l32; d < D_EMB; d += 32) { float v = clip[r][d]; ss += v * v; }
#pragma unroll
    for (int off = 16; off; off >>= 1) ss += __shfl_xor(ss, off);
    if (l32 == 0) norms[r] = sqrtf(ss) + 1e-6f;
  }
  __syncthreads();
  {
    int p = t >> 2, sub = t & 3;
    int i = p >> 3, j = p & 7;
    float s = 0;
    for (int d = sub; d < D_EMB; d += 4) s += clip[i][d] * clip[j][d];
    s += __shfl_xor(s, 1);
    s += __shfl_xor(s, 2);
    if (sub == 0) sc[i][j] = s / (norms[i] * norms[j]);
  }
  __syncthreads();
  const float inv_tls = 1.f / (__expf(tau_lp[0]) * SQRT_D);
  if (t < 64) {
    int i = t >> 3, j = t & 7;
    float v = sc[i][j] * inv_tls;
    float mx = v;
#pragma unroll
    for (int off = 1; off < 8; off <<= 1) mx = fmaxf(mx, __shfl_xor(mx, off));
    float e = __expf(v - mx);
    float s = e;
#pragma unroll
    for (int off = 1; off < 8; off <<= 1) s += __shfl_xor(s, off);
    sc[i][j] = e / s;
  }
  __syncthreads();
  {
    int r = t >> 5, l32 = t & 31;
    float w[8];
#pragma unroll
    for (int j = 0; j < 8; ++j) w[j] = sc[r][j];
    float accv[36];
    float rs = 0;
#pragma unroll
    for (int kk = 0; kk < 36; ++kk) {
      int d = l32 + kk * 32;
      float a = 0;
#pragma unroll
      for (int j = 0; j < 8; ++j) a += w[j] * clip[j][d];
      accv[kk] = a;
      rs += a * a;
    }
#pragma unroll
    for (int off = 16; off; off >>= 1) rs += __shfl_xor(rs, off);
    if (l32 == 0) nrm2[r] = rs;
    __syncthreads();
    float invn = 1.f / sqrtf(nrm2[r]);
#pragma unroll
    for (int kk = 0; kk < 36; ++kk) {
      int d = l32 + kk * 32;
      loc_n[(size_t)(c * 8 + r) * D_EMB + d] = f2bf(accv[kk] * invn);
    }
  }
}

// ---------------- generic bf16 GEMM: C = A . Bt^T, split-K over blockIdx.z, bf16 partials ----------------
// 128x128 tile, BK=32, 4 waves (2x2 of 64x64), global_load_lds w=16 (m97 structure)
__global__ __launch_bounds__(256) void k_gemm(const u16* __restrict__ A, int lda,
                                              const u16* __restrict__ Bt, int ldb,
                                              u16* __restrict__ Cpart, int ldc,
                                              size_t partStride, int klen) {
  __shared__ __align__(16) u16 As[128 * 32];
  __shared__ __align__(16) u16 Bs[128 * 32];
  const int tid = threadIdx.x;
  const int lane = tid & 63;
  const int wave = tid >> 6;
  const int wr = (wave >> 1) * 64, wc = (wave & 1) * 64;
  const int row0 = blockIdx.x * 128, col0 = blockIdx.y * 128;
  const int kbase = blockIdx.z * klen;
  u16* __restrict__ C = Cpart + (size_t)blockIdx.z * partStride;
  const int srow = tid >> 2;
  const int scol = (tid & 3) * 8;
  const int fr = lane & 15;
  const int fk = (lane >> 4) * 8;
  f32x4 acc[4][4] = {};

  for (int k0 = kbase; k0 < kbase + klen; k0 += 32) {
    gload16(A + (size_t)(row0 + srow) * lda + k0 + scol, As + srow * 32 + scol);
    gload16(A + (size_t)(row0 + 64 + srow) * lda + k0 + scol, As + (64 + srow) * 32 + scol);
    gload16(Bt + (size_t)(col0 + srow) * ldb + k0 + scol, Bs + srow * 32 + scol);
    gload16(Bt + (size_t)(col0 + 64 + srow) * ldb + k0 + scol, Bs + (64 + srow) * 32 + scol);
    __syncthreads();
    bf16x8 af[4], bfr[4];
#pragma unroll
    for (int m = 0; m < 4; ++m) af[m] = *(const bf16x8*)&As[(wr + m * 16 + fr) * 32 + fk];
#pragma unroll
    for (int n = 0; n < 4; ++n) bfr[n] = *(const bf16x8*)&Bs[(wc + n * 16 + fr) * 32 + fk];
#pragma unroll
    for (int m = 0; m < 4; ++m)
#pragma unroll
      for (int n = 0; n < 4; ++n)
        acc[m][n] = __builtin_amdgcn_mfma_f32_16x16x32_bf16(af[m], bfr[n], acc[m][n], 0, 0, 0);
    __syncthreads();
  }
#pragma unroll
  for (int m = 0; m < 4; ++m) {
#pragma unroll
    for (int n = 0; n < 4; ++n) {
      int col = col0 + wc + n * 16 + fr;
#pragma unroll
      for (int r = 0; r < 4; ++r) {
        int row = row0 + wr + m * 16 + (lane >> 4) * 4 + r;
        C[(size_t)row * ldc + col] = f2bf(acc[m][n][r]);
      }
    }
  }
}

// ---------------- reduce 8 bf16 split-K partials -> bf16 ----------------
__global__ __launch_bounds__(256) void k_greduce(const u16* __restrict__ Gpart,
                                                 u16* __restrict__ G, size_t S) {
  const size_t gid = (size_t)blockIdx.x * 256 + threadIdx.x;
  float s[8] = {};
#pragma unroll
  for (int p = 0; p < 8; ++p) {
    uint4 v = *(const uint4*)(Gpart + p * S + gid * 8);
    s[0] += bf2f((u16)(v.x & 0xffff));
    s[1] += bf2f((u16)(v.x >> 16));
    s[2] += bf2f((u16)(v.y & 0xffff));
    s[3] += bf2f((u16)(v.y >> 16));
    s[4] += bf2f((u16)(v.z & 0xffff));
    s[5] += bf2f((u16)(v.z >> 16));
    s[6] += bf2f((u16)(v.w & 0xffff));
    s[7] += bf2f((u16)(v.w >> 16));
  }
  uint4 o;
  o.x = (unsigned)f2bf(s[0]) | ((unsigned)f2bf(s[1]) << 16);
  o.y = (unsigned)f2bf(s[2]) | ((unsigned)f2bf(s[3]) << 16);
  o.z = (unsigned)f2bf(s[4]) | ((unsigned)f2bf(s[5]) << 16);
  o.w = (unsigned)f2bf(s[6]) | ((unsigned)f2bf(s[7]) << 16);
  *(uint4*)(G + gid * 8) = o;
}

// ---------------- O = colsum + inv*(H0+H1) + delta*fe ; row l2norm -> glob_n bf16 ----------------
__global__ __launch_bounds__(256) void k_glob(const float* __restrict__ fe,
                                              const u16* __restrict__ Hpart,
                                              const float* __restrict__ colsum,
                                              u16* __restrict__ glob_n,
                                              const float* __restrict__ tau_gp) {
  const int row = blockIdx.x;
  const int t = threadIdx.x;
  const float inv = 1.f / (__expf(tau_gp[0]) * SQRT_D);
  const float delta = inv * inv * (0.5f + inv * (1.f / 6.f) + inv * inv * (1.f / 24.f));
  const size_t S = (size_t)NFR * D_EMB;
  float4 vv[2];
  float ss = 0.f;
#pragma unroll
  for (int i = 0; i < 2; ++i) {
    int idx = t + i * 256;
    if (idx < 288) {
      float4 f = ((const float4*)(fe + (size_t)row * D_EMB))[idx];
      float4 c = ((const float4*)colsum)[idx];
      ushort4 h0 = *(const ushort4*)(Hpart + (size_t)row * D_EMB + idx * 4);
      ushort4 h1 = *(const ushort4*)(Hpart + S + (size_t)row * D_EMB + idx * 4);
      float4 o;
      o.x = c.x + inv * (bf2f(h0.x) + bf2f(h1.x)) + delta * f.x;
      o.y = c.y + inv * (bf2f(h0.y) + bf2f(h1.y)) + delta * f.y;
      o.z = c.z + inv * (bf2f(h0.z) + bf2f(h1.z)) + delta * f.z;
      o.w = c.w + inv * (bf2f(h0.w) + bf2f(h1.w)) + delta * f.w;
      vv[i] = o;
      ss += o.x * o.x + o.y * o.y + o.z * o.z + o.w * o.w;
    }
  }
#pragma unroll
  for (int off = 32; off; off >>= 1) ss += __shfl_down(ss, off);
  __shared__ float wsum[4];
  if ((t & 63) == 0) wsum[t >> 6] = ss;
  __syncthreads();
  float invn = 1.f / sqrtf(wsum[0] + wsum[1] + wsum[2] + wsum[3]);
#pragma unroll
  for (int i = 0; i < 2; ++i) {
    int idx = t + i * 256;
    if (idx < 288) {
      float4 v = vv[i];
      u16 a = f2bf(v.x * invn), b = f2bf(v.y * invn), c = f2bf(v.z * invn), d = f2bf(v.w * invn);
      uint2 pk;
      pk.x = (unsigned)a | ((unsigned)b << 16);
      pk.y = (unsigned)c | ((unsigned)d << 16);
      *(uint2*)(glob_n + (size_t)row * D_EMB + idx * 4) = pk;
    }
  }
}

// ---------------- te scores + fuse + max over queries -> logits[4096] ----------------
#define ACC8(dst, r, tp)                                                            \
  dst += bf2f(tp[0]) * bf2f((u16)(r.x & 0xffff)) + bf2f(tp[1]) * bf2f((u16)(r.x >> 16)) + \
         bf2f(tp[2]) * bf2f((u16)(r.y & 0xffff)) + bf2f(tp[3]) * bf2f((u16)(r.y >> 16)) + \
         bf2f(tp[4]) * bf2f((u16)(r.z & 0xffff)) + bf2f(tp[5]) * bf2f((u16)(r.z >> 16)) + \
         bf2f(tp[6]) * bf2f((u16)(r.w & 0xffff)) + bf2f(tp[7]) * bf2f((u16)(r.w >> 16));

__global__ __launch_bounds__(256) void k_score_max(const u16* __restrict__ te_n,
                                                   const u16* __restrict__ nf,
                                                   const u16* __restrict__ loc_n,
                                                   const u16* __restrict__ glob_n,
                                                   float* __restrict__ logits,
                                                   const float* __restrict__ lsp,
                                                   const float* __restrict__ lbp) {
  __shared__ u16 te16[16][1160];
  const int t = threadIdx.x;
  for (int idx = t; idx < 16 * D_EMB; idx += 256) {
    int q = idx / D_EMB, d = idx - q * D_EMB;
    te16[q][d] = te_n[idx];
  }
  __syncthreads();
  const int q = t & 15;
  const int fl = t >> 4;
  const int frame = blockIdx.x * 16 + fl;
  const uint4* an = (const uint4*)(nf + (size_t)frame * D_EMB);
  const uint4* al = (const uint4*)(loc_n + (size_t)frame * D_EMB);
  const uint4* ag = (const uint4*)(glob_n + (size_t)frame * D_EMB);
  float d0 = 0, d1 = 0, d2 = 0;
  const u16* tq = te16[q];
  for (int ch = 0; ch < 144; ++ch) {
    uint4 ra = an[ch], rb = al[ch], rc = ag[ch];
    const u16* tp = tq + ch * 8;
    ACC8(d0, ra, tp)
    ACC8(d1, rb, tp)
    ACC8(d2, rc, tp)
  }
  float fused = __expf(lsp[0]) * (0.9f * d0 + 0.05f * d1 + 0.05f * d2) + lbp[0];
#pragma unroll
  for (int off = 1; off < 16; off <<= 1) fused = fmaxf(fused, __shfl_xor(fused, off));
  if (q == 0) logits[frame] = fused;
}

// ---------------- softmax-pool per clip + loss ----------------
__global__ __launch_bounds__(512) void k_final(const float* __restrict__ logits,
                                               const float* __restrict__ labels,
                                               float* __restrict__ out) {
  const int t = threadIdx.x;
  float x[8];
  float m = -1e30f;
#pragma unroll
  for (int j = 0; j < 8; ++j) { x[j] = logits[t * 8 + j]; m = fmaxf(m, x[j]); }
  float se = 0, swx = 0;
#pragma unroll
  for (int j = 0; j < 8; ++j) { float e = __expf(x[j] - m); se += e; swx += e * x[j]; }
  float pooled = swx / se;
  out[1 + t] = pooled;
  float lab = labels[t * 8];
  __shared__ float red[8];
  float v = lab;
#pragma unroll
  for (int off = 32; off; off >>= 1) v += __shfl_down(v, off);
  if ((t & 63) == 0) red[t >> 6] = v;
  __syncthreads();
  float total = 0;
#pragma unroll
  for (int w = 0; w < 8; ++w) total += red[w];
  float mean = total * (1.f / 512.f);
  float wgt = pooled * (lab - mean);
  float lsg = (wgt >= 0.f) ? -log1pf(__expf(-wgt)) : (wgt - log1pf(__expf(wgt)));
  __syncthreads();
  float v2 = lsg;
#pragma unroll
  for (int off = 32; off; off >>= 1) v2 += __shfl_down(v2, off);
  if ((t & 63) == 0) red[t >> 6] = v2;
  __syncthreads();
  if (t == 0) {
    float tl = 0;
#pragma unroll
    for (int w = 0; w < 8; ++w) tl += red[w];
    out[0] = -tl;
  }
}

extern "C" void kernel_launch(void* const* d_in, const int* in_sizes, int n_in,
                              void* d_out, int out_size, void* d_ws, size_t ws_size,
                              hipStream_t stream) {
  const float* fe = (const float*)d_in[0];
  const float* text = (const float*)d_in[1];
  const float* labels = (const float*)d_in[2];
  const float* tau_lp = (const float*)d_in[3];
  const float* tau_gp = (const float*)d_in[4];
  const float* lsp = (const float*)d_in[5];
  const float* lbp = (const float*)d_in[6];
  float* out = (float*)d_out;
  char* ws = (char*)d_ws;

  // ws layout (bytes), all 256-aligned, total ~90.6 MB:
  u16* nf = (u16*)(ws + 0);                    // 4096x1152 bf16
  u16* feT = (u16*)(ws + 9437184);             // 1152x4096 bf16
  u16* nfT = (u16*)(ws + 18874368);            // 1152x4096 bf16
  u16* loc_n = (u16*)(ws + 28311552);          // 4096x1152 bf16
  u16* glob_n = (u16*)(ws + 37748736);         // 4096x1152 bf16
  u16* te_n = (u16*)(ws + 47185920);           // 16x1152 bf16
  float* invr = (float*)(ws + 47222784);       // 4096 f32 (1/(norm+eps))
  float* invr_dummy = (float*)(ws + 47239168); // 16 f32
  float* colsum = (float*)(ws + 47239424);     // 1152 f32
  float* kpart = (float*)(ws + 47244032);      // 128x1152 f32 colsum partials
  float* logits = (float*)(ws + 47833856);     // 4096 f32
  u16* G = (u16*)(ws + 47850240);              // 1152x1152 bf16
  u16* Gpart = (u16*)(ws + 50504448);          // 8 x 1152x1152 bf16
  u16* Hpart = (u16*)(ws + 71738112);          // 2 x 4096x1152 bf16

  const size_t GS = (size_t)D_EMB * D_EMB;
  const size_t HS = (size_t)NFR * D_EMB;

  hipLaunchKernelGGL(k_norm_rows, dim3(4096), dim3(256), 0, stream, fe, nf, invr, 1e-6f);
  hipLaunchKernelGGL(k_norm_rows, dim3(16), dim3(256), 0, stream, text, te_n, invr_dummy, 0.f);
  hipLaunchKernelGGL(k_transpose_colsum, dim3(128, 36), dim3(32, 8), 0, stream, fe, feT, kpart);
  hipLaunchKernelGGL(k_colsum_reduce, dim3(9), dim3(128), 0, stream, kpart, colsum);
  hipLaunchKernelGGL(k_scale_cols, dim3(2304), dim3(256), 0, stream, feT, invr, nfT);
  hipLaunchKernelGGL(k_local, dim3(512), dim3(256), 0, stream, fe, loc_n, tau_lp);
  // G = nf^T . fe  (M=N=1152, K=4096, split 8)
  hipLaunchKernelGGL(k_gemm, dim3(9, 9, 8), dim3(256), 0, stream, nfT, NFR, feT, NFR, Gpart,
                     D_EMB, GS, 512);
  hipLaunchKernelGGL(k_greduce, dim3(648), dim3(256), 0, stream, Gpart, G, GS);
  // H = nf . G  (M=4096, N=1152, K=1152, split 2; G symmetric so Bt = G)
  hipLaunchKernelGGL(k_gemm, dim3(32, 9, 2), dim3(256), 0, stream, nf, D_EMB, G, D_EMB, Hpart,
                     D_EMB, HS, 576);
  hipLaunchKernelGGL(k_glob, dim3(4096), dim3(256), 0, stream, fe, Hpart, colsum, glob_n, tau_gp);
  hipLaunchKernelGGL(k_score_max, dim3(256), dim3(256), 0, stream, te_n, nf, loc_n, glob_n,
                     logits, lsp, lbp);
  hipLaunchKernelGGL(k_final, dim3(1), dim3(512), 0, stream, logits, labels, out);
}

// Round 4
// 134.908 us; speedup vs baseline: 1.6959x; 1.1103x over previous
//
#include <hip/hip_runtime.h>
#include <math.h>

typedef unsigned short u16;
typedef __attribute__((ext_vector_type(8))) short bf16x8;
typedef __attribute__((ext_vector_type(4))) float f32x4;

#define D_EMB 1152
#define NFR 4096
#define SQRT_D 33.94112549695428f

__device__ __forceinline__ u16 f2bf(float f) {
  unsigned u = __float_as_uint(f);
  u = (u + 0x7FFFu + ((u >> 16) & 1u)) >> 16;
  return (u16)u;
}
__device__ __forceinline__ float bf2f(u16 h) { return __uint_as_float(((unsigned)h) << 16); }

__device__ __forceinline__ void gload16(const void* g, void* l) {
  __builtin_amdgcn_global_load_lds((const __attribute__((address_space(1))) void*)g,
                                   (__attribute__((address_space(3))) void*)l, 16, 0, 0);
}

// ---------------- row l2-normalize (D=1152) -> bf16 (text only now) ----------------
__global__ __launch_bounds__(256) void k_norm_rows(const float* __restrict__ X,
                                                   u16* __restrict__ Y,
                                                   float* __restrict__ invout, float eps) {
  const int row = blockIdx.x;
  const float* x = X + (size_t)row * D_EMB;
  const int t = threadIdx.x;
  float4 vv[2];
  float ss = 0.f;
#pragma unroll
  for (int i = 0; i < 2; ++i) {
    int idx = t + i * 256;
    if (idx < 288) {
      float4 v = ((const float4*)x)[idx];
      vv[i] = v;
      ss += v.x * v.x + v.y * v.y + v.z * v.z + v.w * v.w;
    }
  }
#pragma unroll
  for (int off = 32; off; off >>= 1) ss += __shfl_down(ss, off);
  __shared__ float wsum[4];
  if ((t & 63) == 0) wsum[t >> 6] = ss;
  __syncthreads();
  float inv = 1.f / (sqrtf(wsum[0] + wsum[1] + wsum[2] + wsum[3]) + eps);
  if (t == 0) invout[row] = inv;
#pragma unroll
  for (int i = 0; i < 2; ++i) {
    int idx = t + i * 256;
    if (idx < 288) {
      float4 v = vv[i];
      u16 a = f2bf(v.x * inv), b = f2bf(v.y * inv), c = f2bf(v.z * inv), d = f2bf(v.w * inv);
      uint2 pk;
      pk.x = (unsigned)a | ((unsigned)b << 16);
      pk.y = (unsigned)c | ((unsigned)d << 16);
      *(uint2*)(Y + (size_t)row * D_EMB + idx * 4) = pk;
    }
  }
}

// ------- transpose fe -> feT bf16 + nfT = feT * invr[k] + per-kblock colsum partials -------
__global__ void k_transpose_colsum(const float* __restrict__ X, const float* __restrict__ invr,
                                   u16* __restrict__ feT, u16* __restrict__ nfT,
                                   float* __restrict__ kpart) {
  __shared__ float tile[32][33];
  __shared__ float cred[8][32];
  const int k0 = blockIdx.x * 32;
  const int d0 = blockIdx.y * 32;
  const int tx = threadIdx.x, ty = threadIdx.y;
  float cs = 0.f;
#pragma unroll
  for (int s = 0; s < 4; ++s) {
    float v = X[(size_t)(k0 + ty + 8 * s) * D_EMB + d0 + tx];
    tile[ty + 8 * s][tx] = v;
    cs += v;
  }
  cred[ty][tx] = cs;
  __syncthreads();
  const float myinv = invr[k0 + tx];
#pragma unroll
  for (int i = ty; i < 32; i += 8) {
    float v = tile[tx][i];
    feT[(size_t)(d0 + i) * NFR + k0 + tx] = f2bf(v);
    nfT[(size_t)(d0 + i) * NFR + k0 + tx] = f2bf(v * myinv);
  }
  if (ty == 0) {
    float s = 0.f;
#pragma unroll
    for (int w = 0; w < 8; ++w) s += cred[w][tx];
    kpart[blockIdx.x * D_EMB + d0 + tx] = s;
  }
}

// ---------------- reduce column-sum partials ----------------
__global__ __launch_bounds__(128) void k_colsum_reduce(const float* __restrict__ kpart,
                                                       float* __restrict__ colsum) {
  const int col = blockIdx.x * 128 + threadIdx.x;
  float s = 0.f;
  for (int kb = 0; kb < 128; ++kb) s += kpart[kb * D_EMB + col];
  colsum[col] = s;
}

// ---------------- local fusion per clip; also emits nf + invr ----------------
__global__ __launch_bounds__(256) void k_local(const float* __restrict__ fe,
                                               u16* __restrict__ loc_n,
                                               u16* __restrict__ nf,
                                               float* __restrict__ invr,
                                               const float* __restrict__ tau_lp) {
  __shared__ __align__(16) float clip[8][1160];
  __shared__ float norms[8];
  __shared__ float sc[8][8];
  __shared__ float nrm2[8];
  const int c = blockIdx.x;
  const int t = threadIdx.x;
  const float* src = fe + (size_t)c * 8 * D_EMB;
  for (int i = t; i < 2304; i += 256) {
    int r = i / 288, qd = i - r * 288;
    float4 v = ((const float4*)(src + r * D_EMB))[qd];
    *(float4*)&clip[r][qd * 4] = v;
  }
  __syncthreads();
  {
    int r = t >> 5, l32 = t & 31;
    float ss = 0;
    for (int d = l32; d < D_EMB; d += 32) { float v = clip[r][d]; ss += v * v; }
#pragma unroll
    for (int off = 16; off; off >>= 1) ss += __shfl_xor(ss, off);
    if (l32 == 0) norms[r] = sqrtf(ss) + 1e-6f;
  }
  __syncthreads();
  {
    int p = t >> 2, sub = t & 3;
    int i = p >> 3, j = p & 7;
    float s = 0;
    for (int d = sub; d < D_EMB; d += 4) s += clip[i][d] * clip[j][d];
    s += __shfl_xor(s, 1);
    s += __shfl_xor(s, 2);
    if (sub == 0) sc[i][j] = s / (norms[i] * norms[j]);
  }
  __syncthreads();
  const float inv_tls = 1.f / (__expf(tau_lp[0]) * SQRT_D);
  if (t < 64) {
    int i = t >> 3, j = t & 7;
    float v = sc[i][j] * inv_tls;
    float mx = v;
#pragma unroll
    for (int off = 1; off < 8; off <<= 1) mx = fmaxf(mx, __shfl_xor(mx, off));
    float e = __expf(v - mx);
    float s = e;
#pragma unroll
    for (int off = 1; off < 8; off <<= 1) s += __shfl_xor(s, off);
    sc[i][j] = e / s;
  }
  __syncthreads();
  {
    int r = t >> 5, l32 = t & 31;
    float w[8];
#pragma unroll
    for (int j = 0; j < 8; ++j) w[j] = sc[r][j];
    const float invn_nf = 1.f / norms[r];
    if (l32 == 0) invr[c * 8 + r] = invn_nf;
    float accv[36];
    float rs = 0;
#pragma unroll
    for (int kk = 0; kk < 36; ++kk) {
      int d = l32 + kk * 32;
      float a = 0;
#pragma unroll
      for (int j = 0; j < 8; ++j) a += w[j] * clip[j][d];
      accv[kk] = a;
      rs += a * a;
      nf[(size_t)(c * 8 + r) * D_EMB + d] = f2bf(clip[r][d] * invn_nf);
    }
#pragma unroll
    for (int off = 16; off; off >>= 1) rs += __shfl_xor(rs, off);
    if (l32 == 0) nrm2[r] = rs;
    __syncthreads();
    float invn = 1.f / sqrtf(nrm2[r]);
#pragma unroll
    for (int kk = 0; kk < 36; ++kk) {
      int d = l32 + kk * 32;
      loc_n[(size_t)(c * 8 + r) * D_EMB + d] = f2bf(accv[kk] * invn);
    }
  }
}

// ---------------- generic bf16 GEMM: C = A . Bt^T, split-K, bf16 partials ----------------
__global__ __launch_bounds__(256) void k_gemm(const u16* __restrict__ A, int lda,
                                              const u16* __restrict__ Bt, int ldb,
                                              u16* __restrict__ Cpart, int ldc,
                                              size_t partStride, int klen) {
  __shared__ __align__(16) u16 As[128 * 32];
  __shared__ __align__(16) u16 Bs[128 * 32];
  const int tid = threadIdx.x;
  const int lane = tid & 63;
  const int wave = tid >> 6;
  const int wr = (wave >> 1) * 64, wc = (wave & 1) * 64;
  const int row0 = blockIdx.x * 128, col0 = blockIdx.y * 128;
  const int kbase = blockIdx.z * klen;
  u16* __restrict__ C = Cpart + (size_t)blockIdx.z * partStride;
  const int srow = tid >> 2;
  const int scol = (tid & 3) * 8;
  const int fr = lane & 15;
  const int fk = (lane >> 4) * 8;
  f32x4 acc[4][4] = {};

  for (int k0 = kbase; k0 < kbase + klen; k0 += 32) {
    gload16(A + (size_t)(row0 + srow) * lda + k0 + scol, As + srow * 32 + scol);
    gload16(A + (size_t)(row0 + 64 + srow) * lda + k0 + scol, As + (64 + srow) * 32 + scol);
    gload16(Bt + (size_t)(col0 + srow) * ldb + k0 + scol, Bs + srow * 32 + scol);
    gload16(Bt + (size_t)(col0 + 64 + srow) * ldb + k0 + scol, Bs + (64 + srow) * 32 + scol);
    __syncthreads();
    bf16x8 af[4], bfr[4];
#pragma unroll
    for (int m = 0; m < 4; ++m) af[m] = *(const bf16x8*)&As[(wr + m * 16 + fr) * 32 + fk];
#pragma unroll
    for (int n = 0; n < 4; ++n) bfr[n] = *(const bf16x8*)&Bs[(wc + n * 16 + fr) * 32 + fk];
#pragma unroll
    for (int m = 0; m < 4; ++m)
#pragma unroll
      for (int n = 0; n < 4; ++n)
        acc[m][n] = __builtin_amdgcn_mfma_f32_16x16x32_bf16(af[m], bfr[n], acc[m][n], 0, 0, 0);
    __syncthreads();
  }
#pragma unroll
  for (int m = 0; m < 4; ++m) {
#pragma unroll
    for (int n = 0; n < 4; ++n) {
      int col = col0 + wc + n * 16 + fr;
#pragma unroll
      for (int r = 0; r < 4; ++r) {
        int row = row0 + wr + m * 16 + (lane >> 4) * 4 + r;
        C[(size_t)row * ldc + col] = f2bf(acc[m][n][r]);
      }
    }
  }
}

// ---------------- reduce 8 bf16 split-K partials -> bf16 ----------------
__global__ __launch_bounds__(256) void k_greduce(const u16* __restrict__ Gpart,
                                                 u16* __restrict__ G, size_t S) {
  const size_t gid = (size_t)blockIdx.x * 256 + threadIdx.x;
  float s[8] = {};
#pragma unroll
  for (int p = 0; p < 8; ++p) {
    uint4 v = *(const uint4*)(Gpart + p * S + gid * 8);
    s[0] += bf2f((u16)(v.x & 0xffff));
    s[1] += bf2f((u16)(v.x >> 16));
    s[2] += bf2f((u16)(v.y & 0xffff));
    s[3] += bf2f((u16)(v.y >> 16));
    s[4] += bf2f((u16)(v.z & 0xffff));
    s[5] += bf2f((u16)(v.z >> 16));
    s[6] += bf2f((u16)(v.w & 0xffff));
    s[7] += bf2f((u16)(v.w >> 16));
  }
  uint4 o;
  o.x = (unsigned)f2bf(s[0]) | ((unsigned)f2bf(s[1]) << 16);
  o.y = (unsigned)f2bf(s[2]) | ((unsigned)f2bf(s[3]) << 16);
  o.z = (unsigned)f2bf(s[4]) | ((unsigned)f2bf(s[5]) << 16);
  o.w = (unsigned)f2bf(s[6]) | ((unsigned)f2bf(s[7]) << 16);
  *(uint4*)(G + gid * 8) = o;
}

// ---------------- tg_v = G . te_v (bf16), tec_v = te_v . c, cs2 = ||c||^2 ----------------
__global__ __launch_bounds__(256) void k_gte(const u16* __restrict__ G,
                                             const u16* __restrict__ te_n,
                                             const float* __restrict__ colsum,
                                             u16* __restrict__ tg,
                                             float* __restrict__ tec) {
  const int v = blockIdx.y;   // 0..16 (16 = colsum itself)
  const int db = blockIdx.x;  // 0..9 (9 = scalar dots)
  if (v == 16 && db < 9) return;  // gc not needed
  const int t = threadIdx.x;
  __shared__ float vec[1152];
  __shared__ float red[4];
  for (int i = t; i < D_EMB; i += 256)
    vec[i] = (v < 16) ? bf2f(te_n[v * D_EMB + i]) : colsum[i];
  __syncthreads();
  if (db < 9) {
    const int j = t >> 1, half = t & 1;
    const int d = db * 128 + j;
    const u16* grow = G + (size_t)d * D_EMB + half * 576;
    const float* vp = vec + half * 576;
    float s = 0.f;
    for (int ch = 0; ch < 72; ++ch) {
      uint4 g = *(const uint4*)(grow + ch * 8);
      const float* v8 = vp + ch * 8;
      s += bf2f((u16)(g.x & 0xffff)) * v8[0] + bf2f((u16)(g.x >> 16)) * v8[1] +
           bf2f((u16)(g.y & 0xffff)) * v8[2] + bf2f((u16)(g.y >> 16)) * v8[3] +
           bf2f((u16)(g.z & 0xffff)) * v8[4] + bf2f((u16)(g.z >> 16)) * v8[5] +
           bf2f((u16)(g.w & 0xffff)) * v8[6] + bf2f((u16)(g.w >> 16)) * v8[7];
    }
    s += __shfl_xor(s, 1);
    if (half == 0) tg[v * D_EMB + d] = f2bf(s);
  } else {
    float s = 0.f;
    for (int i = t; i < D_EMB; i += 256) s += vec[i] * colsum[i];
#pragma unroll
    for (int off = 32; off; off >>= 1) s += __shfl_down(s, off);
    if ((t & 63) == 0) red[t >> 6] = s;
    __syncthreads();
    if (t == 0) tec[v] = red[0] + red[1] + red[2] + red[3];  // v==16 -> cs2
  }
}

// ---------------- te scores + projected-glob + fuse + max over queries ----------------
#define ACC8(dst, r, tp)                                                            \
  dst += bf2f(tp[0]) * bf2f((u16)(r.x & 0xffff)) + bf2f(tp[1]) * bf2f((u16)(r.x >> 16)) + \
         bf2f(tp[2]) * bf2f((u16)(r.y & 0xffff)) + bf2f(tp[3]) * bf2f((u16)(r.y >> 16)) + \
         bf2f(tp[4]) * bf2f((u16)(r.z & 0xffff)) + bf2f(tp[5]) * bf2f((u16)(r.z >> 16)) + \
         bf2f(tp[6]) * bf2f((u16)(r.w & 0xffff)) + bf2f(tp[7]) * bf2f((u16)(r.w >> 16));

__global__ __launch_bounds__(256) void k_score_max(const u16* __restrict__ te_n,
                                                   const u16* __restrict__ nf,
                                                   const u16* __restrict__ loc_n,
                                                   const u16* __restrict__ tgv,
                                                   const float* __restrict__ tec,
                                                   const float* __restrict__ invr,
                                                   float* __restrict__ logits,
                                                   const float* __restrict__ tau_gp,
                                                   const float* __restrict__ lsp,
                                                   const float* __restrict__ lbp) {
  __shared__ u16 te16[16][1160];
  __shared__ u16 tg16[16][1160];
  const int t = threadIdx.x;
  for (int idx = t; idx < 16 * D_EMB; idx += 256) {
    int q = idx / D_EMB, d = idx - q * D_EMB;
    te16[q][d] = te_n[idx];
    tg16[q][d] = tgv[idx];
  }
  __syncthreads();
  const int q = t & 15;
  const int fl = t >> 4;
  const int frame = blockIdx.x * 16 + fl;
  const uint4* an = (const uint4*)(nf + (size_t)frame * D_EMB);
  const uint4* al = (const uint4*)(loc_n + (size_t)frame * D_EMB);
  float d0 = 0, d1 = 0, dtg = 0;
  const u16* tq = te16[q];
  const u16* gq = tg16[q];
  for (int ch = 0; ch < 144; ++ch) {
    uint4 ra = an[ch], rb = al[ch];
    const u16* tp = tq + ch * 8;
    const u16* gp = gq + ch * 8;
    ACC8(d0, ra, tp)
    ACC8(d1, rb, tp)
    ACC8(dtg, ra, gp)
  }
  const float inv = 1.f / (__expf(tau_gp[0]) * SQRT_D);
  const float delta = inv * inv * (0.5f + inv * (1.f / 6.f) + inv * inv * (1.f / 24.f));
  const float rn = 1.f / invr[frame];  // ||f_r|| + eps
  const float rsq = rsqrtf(tec[16]);   // 1/||c||
  float glob = (tec[q] + inv * dtg + delta * d0 * rn) * rsq;
  float fused = __expf(lsp[0]) * (0.9f * d0 + 0.05f * d1 + 0.05f * glob) + lbp[0];
#pragma unroll
  for (int off = 1; off < 16; off <<= 1) fused = fmaxf(fused, __shfl_xor(fused, off));
  if (q == 0) logits[frame] = fused;
}

// ---------------- softmax-pool per clip + loss ----------------
__global__ __launch_bounds__(512) void k_final(const float* __restrict__ logits,
                                               const float* __restrict__ labels,
                                               float* __restrict__ out) {
  const int t = threadIdx.x;
  float x[8];
  float m = -1e30f;
#pragma unroll
  for (int j = 0; j < 8; ++j) { x[j] = logits[t * 8 + j]; m = fmaxf(m, x[j]); }
  float se = 0, swx = 0;
#pragma unroll
  for (int j = 0; j < 8; ++j) { float e = __expf(x[j] - m); se += e; swx += e * x[j]; }
  float pooled = swx / se;
  out[1 + t] = pooled;
  float lab = labels[t * 8];
  __shared__ float red[8];
  float v = lab;
#pragma unroll
  for (int off = 32; off; off >>= 1) v += __shfl_down(v, off);
  if ((t & 63) == 0) red[t >> 6] = v;
  __syncthreads();
  float total = 0;
#pragma unroll
  for (int w = 0; w < 8; ++w) total += red[w];
  float mean = total * (1.f / 512.f);
  float wgt = pooled * (lab - mean);
  float lsg = (wgt >= 0.f) ? -log1pf(__expf(-wgt)) : (wgt - log1pf(__expf(wgt)));
  __syncthreads();
  float v2 = lsg;
#pragma unroll
  for (int off = 32; off; off >>= 1) v2 += __shfl_down(v2, off);
  if ((t & 63) == 0) red[t >> 6] = v2;
  __syncthreads();
  if (t == 0) {
    float tl = 0;
#pragma unroll
    for (int w = 0; w < 8; ++w) tl += red[w];
    out[0] = -tl;
  }
}

extern "C" void kernel_launch(void* const* d_in, const int* in_sizes, int n_in,
                              void* d_out, int out_size, void* d_ws, size_t ws_size,
                              hipStream_t stream) {
  const float* fe = (const float*)d_in[0];
  const float* text = (const float*)d_in[1];
  const float* labels = (const float*)d_in[2];
  const float* tau_lp = (const float*)d_in[3];
  const float* tau_gp = (const float*)d_in[4];
  const float* lsp = (const float*)d_in[5];
  const float* lbp = (const float*)d_in[6];
  float* out = (float*)d_out;
  char* ws = (char*)d_ws;

  // ws layout (bytes), 256-aligned, total ~62.3 MB:
  u16* nf = (u16*)(ws + 0);                   // 4096x1152 bf16
  u16* feT = (u16*)(ws + 9437184);            // 1152x4096 bf16
  u16* nfT = (u16*)(ws + 18874368);           // 1152x4096 bf16
  u16* loc_n = (u16*)(ws + 28311552);         // 4096x1152 bf16
  u16* te_n = (u16*)(ws + 37748736);          // 16x1152 bf16
  float* invr = (float*)(ws + 37785600);      // 4096 f32
  float* invr_txt = (float*)(ws + 37801984);  // 16 f32 (unused)
  float* colsum = (float*)(ws + 37802240);    // 1152 f32
  float* kpart = (float*)(ws + 37806848);     // 128x1152 f32
  float* logits = (float*)(ws + 38396672);    // 4096 f32
  float* tec = (float*)(ws + 38413056);       // 17 f32 (tec[0..15], cs2 at [16])
  u16* tg = (u16*)(ws + 38413312);            // 16x1152 bf16
  u16* G = (u16*)(ws + 38450176);             // 1152x1152 bf16
  u16* Gpart = (u16*)(ws + 41104384);         // 8 x 1152x1152 bf16

  const size_t GS = (size_t)D_EMB * D_EMB;

  hipLaunchKernelGGL(k_norm_rows, dim3(16), dim3(256), 0, stream, text, te_n, invr_txt, 0.f);
  hipLaunchKernelGGL(k_local, dim3(512), dim3(256), 0, stream, fe, loc_n, nf, invr, tau_lp);
  hipLaunchKernelGGL(k_transpose_colsum, dim3(128, 36), dim3(32, 8), 0, stream, fe, invr, feT,
                     nfT, kpart);
  hipLaunchKernelGGL(k_colsum_reduce, dim3(9), dim3(128), 0, stream, kpart, colsum);
  // G = nf^T . fe  (M=N=1152, K=4096, split 8)
  hipLaunchKernelGGL(k_gemm, dim3(9, 9, 8), dim3(256), 0, stream, nfT, NFR, feT, NFR, Gpart,
                     D_EMB, GS, 512);
  hipLaunchKernelGGL(k_greduce, dim3(648), dim3(256), 0, stream, Gpart, G, GS);
  hipLaunchKernelGGL(k_gte, dim3(10, 17), dim3(256), 0, stream, G, te_n, colsum, tg, tec);
  hipLaunchKernelGGL(k_score_max, dim3(256), dim3(256), 0, stream, te_n, nf, loc_n, tg, tec,
                     invr, logits, tau_gp, lsp, lbp);
  hipLaunchKernelGGL(k_final, dim3(1), dim3(512), 0, stream, logits, labels, out);
}

// Round 5
// 92.135 us; speedup vs baseline: 2.4832x; 1.4642x over previous
//
#include <hip/hip_runtime.h>
#include <math.h>

typedef unsigned short u16;
typedef __attribute__((ext_vector_type(8))) short bf16x8;
typedef __attribute__((ext_vector_type(4))) float f32x4;

#define D_EMB 1152
#define NFR 4096
#define SQRT_D 33.94112549695428f

__device__ __forceinline__ u16 f2bf(float f) {
  unsigned u = __float_as_uint(f);
  u = (u + 0x7FFFu + ((u >> 16) & 1u)) >> 16;
  return (u16)u;
}
__device__ __forceinline__ float bf2f(u16 h) { return __uint_as_float(((unsigned)h) << 16); }

__device__ __forceinline__ void gload16(const void* g, void* l) {
  __builtin_amdgcn_global_load_lds((const __attribute__((address_space(1))) void*)g,
                                   (__attribute__((address_space(3))) void*)l, 16, 0, 0);
}

// ------- transpose fe -> feT bf16 + nfT = feT * invr[k] + per-kblock colsum partials -------
__global__ void k_transpose_colsum(const float* __restrict__ X, const float* __restrict__ invr,
                                   u16* __restrict__ feT, u16* __restrict__ nfT,
                                   float* __restrict__ kpart) {
  __shared__ float tile[32][33];
  __shared__ float cred[8][32];
  const int k0 = blockIdx.x * 32;
  const int d0 = blockIdx.y * 32;
  const int tx = threadIdx.x, ty = threadIdx.y;
  float cs = 0.f;
#pragma unroll
  for (int s = 0; s < 4; ++s) {
    float v = X[(size_t)(k0 + ty + 8 * s) * D_EMB + d0 + tx];
    tile[ty + 8 * s][tx] = v;
    cs += v;
  }
  cred[ty][tx] = cs;
  __syncthreads();
  const float myinv = invr[k0 + tx];
#pragma unroll
  for (int i = ty; i < 32; i += 8) {
    float v = tile[tx][i];
    feT[(size_t)(d0 + i) * NFR + k0 + tx] = f2bf(v);
    nfT[(size_t)(d0 + i) * NFR + k0 + tx] = f2bf(v * myinv);
  }
  if (ty == 0) {
    float s = 0.f;
#pragma unroll
    for (int w = 0; w < 8; ++w) s += cred[w][tx];
    kpart[blockIdx.x * D_EMB + d0 + tx] = s;
  }
}

// ---------------- reduce column-sum partials ----------------
__global__ __launch_bounds__(128) void k_colsum_reduce(const float* __restrict__ kpart,
                                                       float* __restrict__ colsum) {
  const int col = blockIdx.x * 128 + threadIdx.x;
  float s = 0.f;
  for (int kb = 0; kb < 128; ++kb) s += kpart[kb * D_EMB + col];
  colsum[col] = s;
}

// ---------------- local fusion per clip; emits loc_n, nf, invr; blocks>=512 do text norm ----------------
__global__ __launch_bounds__(256) void k_local(const float* __restrict__ fe,
                                               const float* __restrict__ text,
                                               u16* __restrict__ loc_n,
                                               u16* __restrict__ nf,
                                               u16* __restrict__ te_n,
                                               float* __restrict__ invr,
                                               const float* __restrict__ tau_lp) {
  __shared__ __align__(16) float clip[8][1160];
  __shared__ float norms[8];
  __shared__ float sc[8][8];
  __shared__ float nrm2[8];
  __shared__ float wsum2[4];
  const int t = threadIdx.x;

  if (blockIdx.x >= 512) {  // ---- text row l2norm (eps=0) ----
    const int row = blockIdx.x - 512;
    const float* x = text + (size_t)row * D_EMB;
    float4 vv[2];
    float ss = 0.f;
#pragma unroll
    for (int i = 0; i < 2; ++i) {
      int idx = t + i * 256;
      if (idx < 288) {
        float4 v = ((const float4*)x)[idx];
        vv[i] = v;
        ss += v.x * v.x + v.y * v.y + v.z * v.z + v.w * v.w;
      }
    }
#pragma unroll
    for (int off = 32; off; off >>= 1) ss += __shfl_down(ss, off);
    if ((t & 63) == 0) wsum2[t >> 6] = ss;
    __syncthreads();
    float inv = 1.f / sqrtf(wsum2[0] + wsum2[1] + wsum2[2] + wsum2[3]);
#pragma unroll
    for (int i = 0; i < 2; ++i) {
      int idx = t + i * 256;
      if (idx < 288) {
        float4 v = vv[i];
        u16 a = f2bf(v.x * inv), b = f2bf(v.y * inv), c = f2bf(v.z * inv), d = f2bf(v.w * inv);
        uint2 pk;
        pk.x = (unsigned)a | ((unsigned)b << 16);
        pk.y = (unsigned)c | ((unsigned)d << 16);
        *(uint2*)(te_n + (size_t)row * D_EMB + idx * 4) = pk;
      }
    }
    return;
  }

  const int c = blockIdx.x;
  const float* src = fe + (size_t)c * 8 * D_EMB;
  for (int i = t; i < 2304; i += 256) {
    int r = i / 288, qd = i - r * 288;
    float4 v = ((const float4*)(src + r * D_EMB))[qd];
    *(float4*)&clip[r][qd * 4] = v;
  }
  __syncthreads();
  {
    int r = t >> 5, l32 = t & 31;
    float ss = 0;
    for (int d = l32; d < D_EMB; d += 32) { float v = clip[r][d]; ss += v * v; }
#pragma unroll
    for (int off = 16; off; off >>= 1) ss += __shfl_xor(ss, off);
    if (l32 == 0) norms[r] = sqrtf(ss) + 1e-6f;
  }
  __syncthreads();
  {
    int p = t >> 2, sub = t & 3;
    int i = p >> 3, j = p & 7;
    float s = 0;
    for (int d = sub; d < D_EMB; d += 4) s += clip[i][d] * clip[j][d];
    s += __shfl_xor(s, 1);
    s += __shfl_xor(s, 2);
    if (sub == 0) sc[i][j] = s / (norms[i] * norms[j]);
  }
  __syncthreads();
  const float inv_tls = 1.f / (__expf(tau_lp[0]) * SQRT_D);
  if (t < 64) {
    int i = t >> 3, j = t & 7;
    float v = sc[i][j] * inv_tls;
    float mx = v;
#pragma unroll
    for (int off = 1; off < 8; off <<= 1) mx = fmaxf(mx, __shfl_xor(mx, off));
    float e = __expf(v - mx);
    float s = e;
#pragma unroll
    for (int off = 1; off < 8; off <<= 1) s += __shfl_xor(s, off);
    sc[i][j] = e / s;
  }
  __syncthreads();
  {
    int r = t >> 5, l32 = t & 31;
    float w[8];
#pragma unroll
    for (int j = 0; j < 8; ++j) w[j] = sc[r][j];
    const float invn_nf = 1.f / norms[r];
    if (l32 == 0) invr[c * 8 + r] = invn_nf;
    float accv[36];
    float rs = 0;
#pragma unroll
    for (int kk = 0; kk < 36; ++kk) {
      int d = l32 + kk * 32;
      float a = 0;
#pragma unroll
      for (int j = 0; j < 8; ++j) a += w[j] * clip[j][d];
      accv[kk] = a;
      rs += a * a;
      nf[(size_t)(c * 8 + r) * D_EMB + d] = f2bf(clip[r][d] * invn_nf);
    }
#pragma unroll
    for (int off = 16; off; off >>= 1) rs += __shfl_xor(rs, off);
    if (l32 == 0) nrm2[r] = rs;
    __syncthreads();
    float invn = 1.f / sqrtf(nrm2[r]);
#pragma unroll
    for (int kk = 0; kk < 36; ++kk) {
      int d = l32 + kk * 32;
      loc_n[(size_t)(c * 8 + r) * D_EMB + d] = f2bf(accv[kk] * invn);
    }
  }
}

// ------- bf16 GEMM: C = A . Bt^T, split-K, bf16 partials; tri=1 -> upper tile-triangle only -------
__global__ __launch_bounds__(256) void k_gemm(const u16* __restrict__ A, int lda,
                                              const u16* __restrict__ Bt, int ldb,
                                              u16* __restrict__ Cpart, int ldc,
                                              size_t partStride, int klen, int tri) {
  __shared__ __align__(16) u16 As[128 * 32];
  __shared__ __align__(16) u16 Bs[128 * 32];
  int bx, by;
  if (tri) {
    int z = blockIdx.x;
    by = 0;
    while (z > by) { z -= by + 1; ++by; }
    bx = z;  // bx <= by
  } else {
    bx = blockIdx.x;
    by = blockIdx.y;
  }
  const int tid = threadIdx.x;
  const int lane = tid & 63;
  const int wave = tid >> 6;
  const int wr = (wave >> 1) * 64, wc = (wave & 1) * 64;
  const int row0 = bx * 128, col0 = by * 128;
  const int kbase = blockIdx.z * klen;
  u16* __restrict__ C = Cpart + (size_t)blockIdx.z * partStride;
  const int srow = tid >> 2;
  const int scol = (tid & 3) * 8;
  const int fr = lane & 15;
  const int fk = (lane >> 4) * 8;
  f32x4 acc[4][4] = {};

  for (int k0 = kbase; k0 < kbase + klen; k0 += 32) {
    gload16(A + (size_t)(row0 + srow) * lda + k0 + scol, As + srow * 32 + scol);
    gload16(A + (size_t)(row0 + 64 + srow) * lda + k0 + scol, As + (64 + srow) * 32 + scol);
    gload16(Bt + (size_t)(col0 + srow) * ldb + k0 + scol, Bs + srow * 32 + scol);
    gload16(Bt + (size_t)(col0 + 64 + srow) * ldb + k0 + scol, Bs + (64 + srow) * 32 + scol);
    __syncthreads();
    bf16x8 af[4], bfr[4];
#pragma unroll
    for (int m = 0; m < 4; ++m) af[m] = *(const bf16x8*)&As[(wr + m * 16 + fr) * 32 + fk];
#pragma unroll
    for (int n = 0; n < 4; ++n) bfr[n] = *(const bf16x8*)&Bs[(wc + n * 16 + fr) * 32 + fk];
#pragma unroll
    for (int m = 0; m < 4; ++m)
#pragma unroll
      for (int n = 0; n < 4; ++n)
        acc[m][n] = __builtin_amdgcn_mfma_f32_16x16x32_bf16(af[m], bfr[n], acc[m][n], 0, 0, 0);
    __syncthreads();
  }
#pragma unroll
  for (int m = 0; m < 4; ++m) {
#pragma unroll
    for (int n = 0; n < 4; ++n) {
      int col = col0 + wc + n * 16 + fr;
#pragma unroll
      for (int r = 0; r < 4; ++r) {
        int row = row0 + wr + m * 16 + (lane >> 4) * 4 + r;
        C[(size_t)row * ldc + col] = f2bf(acc[m][n][r]);
      }
    }
  }
}

// ---------------- reduce 8 bf16 split-K partials -> G, mirroring upper->lower ----------------
__global__ __launch_bounds__(256) void k_greduce(const u16* __restrict__ Gpart,
                                                 u16* __restrict__ G, size_t S) {
  const size_t gid = (size_t)blockIdx.x * 256 + threadIdx.x;
  const size_t e0 = gid * 8;
  const int row = (int)(e0 / D_EMB);
  const int col = (int)(e0 % D_EMB);
  const int tr = row >> 7, tc = col >> 7;
  if (tc < tr) return;  // lower tiles filled by mirror
  float s[8] = {};
#pragma unroll
  for (int p = 0; p < 8; ++p) {
    uint4 v = *(const uint4*)(Gpart + p * S + e0);
    s[0] += bf2f((u16)(v.x & 0xffff));
    s[1] += bf2f((u16)(v.x >> 16));
    s[2] += bf2f((u16)(v.y & 0xffff));
    s[3] += bf2f((u16)(v.y >> 16));
    s[4] += bf2f((u16)(v.z & 0xffff));
    s[5] += bf2f((u16)(v.z >> 16));
    s[6] += bf2f((u16)(v.w & 0xffff));
    s[7] += bf2f((u16)(v.w >> 16));
  }
  uint4 o;
  o.x = (unsigned)f2bf(s[0]) | ((unsigned)f2bf(s[1]) << 16);
  o.y = (unsigned)f2bf(s[2]) | ((unsigned)f2bf(s[3]) << 16);
  o.z = (unsigned)f2bf(s[4]) | ((unsigned)f2bf(s[5]) << 16);
  o.w = (unsigned)f2bf(s[6]) | ((unsigned)f2bf(s[7]) << 16);
  *(uint4*)(G + e0) = o;
  if (tc > tr) {
#pragma unroll
    for (int j = 0; j < 8; ++j) G[(size_t)(col + j) * D_EMB + row] = f2bf(s[j]);
  }
}

// ---------------- tg_v = G . te_v (bf16), tec_v = te_v . c, cs2 = ||c||^2 ----------------
__global__ __launch_bounds__(256) void k_gte(const u16* __restrict__ G,
                                             const u16* __restrict__ te_n,
                                             const float* __restrict__ colsum,
                                             u16* __restrict__ tg,
                                             float* __restrict__ tec) {
  const int v = blockIdx.y;   // 0..16 (16 = colsum itself)
  const int db = blockIdx.x;  // 0..9 (9 = scalar dots)
  if (v == 16 && db < 9) return;
  const int t = threadIdx.x;
  __shared__ float vec[1152];
  __shared__ float red[4];
  for (int i = t; i < D_EMB; i += 256)
    vec[i] = (v < 16) ? bf2f(te_n[v * D_EMB + i]) : colsum[i];
  __syncthreads();
  if (db < 9) {
    const int j = t >> 1, half = t & 1;
    const int d = db * 128 + j;
    const u16* grow = G + (size_t)d * D_EMB + half * 576;
    const float* vp = vec + half * 576;
    float s = 0.f;
    for (int ch = 0; ch < 72; ++ch) {
      uint4 g = *(const uint4*)(grow + ch * 8);
      const float* v8 = vp + ch * 8;
      s += bf2f((u16)(g.x & 0xffff)) * v8[0] + bf2f((u16)(g.x >> 16)) * v8[1] +
           bf2f((u16)(g.y & 0xffff)) * v8[2] + bf2f((u16)(g.y >> 16)) * v8[3] +
           bf2f((u16)(g.z & 0xffff)) * v8[4] + bf2f((u16)(g.z >> 16)) * v8[5] +
           bf2f((u16)(g.w & 0xffff)) * v8[6] + bf2f((u16)(g.w >> 16)) * v8[7];
    }
    s += __shfl_xor(s, 1);
    if (half == 0) tg[v * D_EMB + d] = f2bf(s);
  } else {
    float s = 0.f;
    for (int i = t; i < D_EMB; i += 256) s += vec[i] * colsum[i];
#pragma unroll
    for (int off = 32; off; off >>= 1) s += __shfl_down(s, off);
    if ((t & 63) == 0) red[t >> 6] = s;
    __syncthreads();
    if (t == 0) tec[v] = red[0] + red[1] + red[2] + red[3];
  }
}

// ---------------- MFMA score: d0/d1/dtg via 16x16x32, fused glob + max epilogue ----------------
__global__ __launch_bounds__(256) void k_score_mfma(const u16* __restrict__ te_n,
                                                    const u16* __restrict__ tgv,
                                                    const u16* __restrict__ nf,
                                                    const u16* __restrict__ loc_n,
                                                    const float* __restrict__ tec,
                                                    const float* __restrict__ invr,
                                                    float* __restrict__ logits,
                                                    const float* __restrict__ tau_gp,
                                                    const float* __restrict__ lsp,
                                                    const float* __restrict__ lbp) {
  const int tid = threadIdx.x;
  const int lane = tid & 63;
  const int wave = tid >> 6;
  const int f0 = blockIdx.x * 16;
  const int fr = lane & 15;          // A-row (query) / B-row (frame) selector
  const int k8 = (lane >> 4) * 8;    // K sub-offset
  const int kbase = wave * 288;      // K split across 4 waves
  f32x4 a0 = {}, a1 = {}, a2 = {};
  const u16* teP = te_n + fr * D_EMB + kbase + k8;
  const u16* tgP = tgv + fr * D_EMB + kbase + k8;
  const u16* nfP = nf + (size_t)(f0 + fr) * D_EMB + kbase + k8;
  const u16* lcP = loc_n + (size_t)(f0 + fr) * D_EMB + kbase + k8;
#pragma unroll
  for (int kc = 0; kc < 9; ++kc) {
    bf16x8 aTe = *(const bf16x8*)(teP + kc * 32);
    bf16x8 aTg = *(const bf16x8*)(tgP + kc * 32);
    bf16x8 bNf = *(const bf16x8*)(nfP + kc * 32);
    bf16x8 bLc = *(const bf16x8*)(lcP + kc * 32);
    a0 = __builtin_amdgcn_mfma_f32_16x16x32_bf16(aTe, bNf, a0, 0, 0, 0);
    a1 = __builtin_amdgcn_mfma_f32_16x16x32_bf16(aTe, bLc, a1, 0, 0, 0);
    a2 = __builtin_amdgcn_mfma_f32_16x16x32_bf16(aTg, bNf, a2, 0, 0, 0);
  }
  __shared__ float red[3][4][256];
#pragma unroll
  for (int r = 0; r < 4; ++r) {
    red[0][wave][lane * 4 + r] = a0[r];
    red[1][wave][lane * 4 + r] = a1[r];
    red[2][wave][lane * 4 + r] = a2[r];
  }
  __syncthreads();
  if (wave == 0) {
    const float inv = 1.f / (__expf(tau_gp[0]) * SQRT_D);
    const float delta = inv * inv * (0.5f + inv * (1.f / 6.f) + inv * inv * (1.f / 24.f));
    const float rn = 1.f / invr[f0 + fr];  // ||f_r|| + eps
    const float rsq = rsqrtf(tec[16]);     // 1/||c||
    const float els = __expf(lsp[0]);
    const float bias = lbp[0];
    float mx = -1e30f;
#pragma unroll
    for (int r = 0; r < 4; ++r) {
      int li = lane * 4 + r;
      float d0 = red[0][0][li] + red[0][1][li] + red[0][2][li] + red[0][3][li];
      float d1 = red[1][0][li] + red[1][1][li] + red[1][2][li] + red[1][3][li];
      float dtg = red[2][0][li] + red[2][1][li] + red[2][2][li] + red[2][3][li];
      int q = (lane >> 4) * 4 + r;
      float glob = (tec[q] + inv * dtg + delta * d0 * rn) * rsq;
      float fused = els * (0.9f * d0 + 0.05f * d1 + 0.05f * glob) + bias;
      mx = fmaxf(mx, fused);
    }
    mx = fmaxf(mx, __shfl_xor(mx, 16));
    mx = fmaxf(mx, __shfl_xor(mx, 32));
    if (lane < 16) logits[f0 + lane] = mx;
  }
}

// ---------------- softmax-pool per clip + loss ----------------
__global__ __launch_bounds__(512) void k_final(const float* __restrict__ logits,
                                               const float* __restrict__ labels,
                                               float* __restrict__ out) {
  const int t = threadIdx.x;
  float x[8];
  float m = -1e30f;
#pragma unroll
  for (int j = 0; j < 8; ++j) { x[j] = logits[t * 8 + j]; m = fmaxf(m, x[j]); }
  float se = 0, swx = 0;
#pragma unroll
  for (int j = 0; j < 8; ++j) { float e = __expf(x[j] - m); se += e; swx += e * x[j]; }
  float pooled = swx / se;
  out[1 + t] = pooled;
  float lab = labels[t * 8];
  __shared__ float red[8];
  float v = lab;
#pragma unroll
  for (int off = 32; off; off >>= 1) v += __shfl_down(v, off);
  if ((t & 63) == 0) red[t >> 6] = v;
  __syncthreads();
  float total = 0;
#pragma unroll
  for (int w = 0; w < 8; ++w) total += red[w];
  float mean = total * (1.f / 512.f);
  float wgt = pooled * (lab - mean);
  float lsg = (wgt >= 0.f) ? -log1pf(__expf(-wgt)) : (wgt - log1pf(__expf(wgt)));
  __syncthreads();
  float v2 = lsg;
#pragma unroll
  for (int off = 32; off; off >>= 1) v2 += __shfl_down(v2, off);
  if ((t & 63) == 0) red[t >> 6] = v2;
  __syncthreads();
  if (t == 0) {
    float tl = 0;
#pragma unroll
    for (int w = 0; w < 8; ++w) tl += red[w];
    out[0] = -tl;
  }
}

extern "C" void kernel_launch(void* const* d_in, const int* in_sizes, int n_in,
                              void* d_out, int out_size, void* d_ws, size_t ws_size,
                              hipStream_t stream) {
  const float* fe = (const float*)d_in[0];
  const float* text = (const float*)d_in[1];
  const float* labels = (const float*)d_in[2];
  const float* tau_lp = (const float*)d_in[3];
  const float* tau_gp = (const float*)d_in[4];
  const float* lsp = (const float*)d_in[5];
  const float* lbp = (const float*)d_in[6];
  float* out = (float*)d_out;
  char* ws = (char*)d_ws;

  // ws layout (bytes), 256-aligned, total ~62.3 MB:
  u16* nf = (u16*)(ws + 0);                   // 4096x1152 bf16
  u16* feT = (u16*)(ws + 9437184);            // 1152x4096 bf16
  u16* nfT = (u16*)(ws + 18874368);           // 1152x4096 bf16
  u16* loc_n = (u16*)(ws + 28311552);         // 4096x1152 bf16
  u16* te_n = (u16*)(ws + 37748736);          // 16x1152 bf16
  float* invr = (float*)(ws + 37785600);      // 4096 f32
  float* colsum = (float*)(ws + 37802240);    // 1152 f32
  float* kpart = (float*)(ws + 37806848);     // 128x1152 f32
  float* logits = (float*)(ws + 38396672);    // 4096 f32
  float* tec = (float*)(ws + 38413056);       // 17 f32
  u16* tg = (u16*)(ws + 38413312);            // 16x1152 bf16
  u16* G = (u16*)(ws + 38450176);             // 1152x1152 bf16
  u16* Gpart = (u16*)(ws + 41104384);         // 8 x 1152x1152 bf16

  const size_t GS = (size_t)D_EMB * D_EMB;

  hipLaunchKernelGGL(k_local, dim3(528), dim3(256), 0, stream, fe, text, loc_n, nf, te_n, invr,
                     tau_lp);
  hipLaunchKernelGGL(k_transpose_colsum, dim3(128, 36), dim3(32, 8), 0, stream, fe, invr, feT,
                     nfT, kpart);
  hipLaunchKernelGGL(k_colsum_reduce, dim3(9), dim3(128), 0, stream, kpart, colsum);
  // G = nf^T . fe  (M=N=1152, K=4096, split 8) — symmetric: upper tile-triangle only (45 tiles)
  hipLaunchKernelGGL(k_gemm, dim3(45, 1, 8), dim3(256), 0, stream, nfT, NFR, feT, NFR, Gpart,
                     D_EMB, GS, 512, 1);
  hipLaunchKernelGGL(k_greduce, dim3(648), dim3(256), 0, stream, Gpart, G, GS);
  hipLaunchKernelGGL(k_gte, dim3(10, 17), dim3(256), 0, stream, G, te_n, colsum, tg, tec);
  hipLaunchKernelGGL(k_score_mfma, dim3(256), dim3(256), 0, stream, te_n, tg, nf, loc_n, tec,
                     invr, logits, tau_gp, lsp, lbp);
  hipLaunchKernelGGL(k_final, dim3(1), dim3(512), 0, stream, logits, labels, out);
}

// Round 6
// 86.062 us; speedup vs baseline: 2.6584x; 1.0706x over previous
//
#include <hip/hip_runtime.h>
#include <math.h>

typedef unsigned short u16;
typedef __attribute__((ext_vector_type(8))) short bf16x8;
typedef __attribute__((ext_vector_type(4))) float f32x4;

#define D_EMB 1152
#define NFR 4096
#define SQRT_D 33.94112549695428f

__device__ __forceinline__ u16 f2bf(float f) {
  unsigned u = __float_as_uint(f);
  u = (u + 0x7FFFu + ((u >> 16) & 1u)) >> 16;
  return (u16)u;
}
__device__ __forceinline__ float bf2f(u16 h) { return __uint_as_float(((unsigned)h) << 16); }

// ------- transpose fe -> nfT = feT * invr[k] (bf16) + per-kblock colsum partials -------
__global__ void k_transpose_colsum(const float* __restrict__ X, const float* __restrict__ invr,
                                   u16* __restrict__ nfT, float* __restrict__ kpart) {
  __shared__ float tile[32][33];
  __shared__ float cred[8][32];
  const int k0 = blockIdx.x * 32;
  const int d0 = blockIdx.y * 32;
  const int tx = threadIdx.x, ty = threadIdx.y;
  float cs = 0.f;
#pragma unroll
  for (int s = 0; s < 4; ++s) {
    float v = X[(size_t)(k0 + ty + 8 * s) * D_EMB + d0 + tx];
    tile[ty + 8 * s][tx] = v;
    cs += v;
  }
  cred[ty][tx] = cs;
  __syncthreads();
  const float myinv = invr[k0 + tx];
#pragma unroll
  for (int i = ty; i < 32; i += 8) {
    float v = tile[tx][i];
    nfT[(size_t)(d0 + i) * NFR + k0 + tx] = f2bf(v * myinv);
  }
  if (ty == 0) {
    float s = 0.f;
#pragma unroll
    for (int w = 0; w < 8; ++w) s += cred[w][tx];
    kpart[blockIdx.x * D_EMB + d0 + tx] = s;
  }
}

// ---------------- reduce column-sum partials ----------------
__global__ __launch_bounds__(128) void k_colsum_reduce(const float* __restrict__ kpart,
                                                       float* __restrict__ colsum) {
  const int col = blockIdx.x * 128 + threadIdx.x;
  float s = 0.f;
  for (int kb = 0; kb < 128; ++kb) s += kpart[kb * D_EMB + col];
  colsum[col] = s;
}

// ---------------- local fusion per clip; emits loc_n, nf, invr; blocks>=512 do text norm ----------------
__global__ __launch_bounds__(256) void k_local(const float* __restrict__ fe,
                                               const float* __restrict__ text,
                                               u16* __restrict__ loc_n,
                                               u16* __restrict__ nf,
                                               u16* __restrict__ te_n,
                                               float* __restrict__ invr,
                                               const float* __restrict__ tau_lp) {
  __shared__ __align__(16) float clip[8][1160];
  __shared__ float norms[8];
  __shared__ float sc[8][8];
  __shared__ float nrm2[8];
  __shared__ float wsum2[4];
  const int t = threadIdx.x;

  if (blockIdx.x >= 512) {  // ---- text row l2norm (eps=0) ----
    const int row = blockIdx.x - 512;
    const float* x = text + (size_t)row * D_EMB;
    float4 vv[2];
    float ss = 0.f;
#pragma unroll
    for (int i = 0; i < 2; ++i) {
      int idx = t + i * 256;
      if (idx < 288) {
        float4 v = ((const float4*)x)[idx];
        vv[i] = v;
        ss += v.x * v.x + v.y * v.y + v.z * v.z + v.w * v.w;
      }
    }
#pragma unroll
    for (int off = 32; off; off >>= 1) ss += __shfl_down(ss, off);
    if ((t & 63) == 0) wsum2[t >> 6] = ss;
    __syncthreads();
    float inv = 1.f / sqrtf(wsum2[0] + wsum2[1] + wsum2[2] + wsum2[3]);
#pragma unroll
    for (int i = 0; i < 2; ++i) {
      int idx = t + i * 256;
      if (idx < 288) {
        float4 v = vv[i];
        u16 a = f2bf(v.x * inv), b = f2bf(v.y * inv), c = f2bf(v.z * inv), d = f2bf(v.w * inv);
        uint2 pk;
        pk.x = (unsigned)a | ((unsigned)b << 16);
        pk.y = (unsigned)c | ((unsigned)d << 16);
        *(uint2*)(te_n + (size_t)row * D_EMB + idx * 4) = pk;
      }
    }
    return;
  }

  const int c = blockIdx.x;
  const float* src = fe + (size_t)c * 8 * D_EMB;
  for (int i = t; i < 2304; i += 256) {
    int r = i / 288, qd = i - r * 288;
    float4 v = ((const float4*)(src + r * D_EMB))[qd];
    *(float4*)&clip[r][qd * 4] = v;
  }
  __syncthreads();
  {
    int r = t >> 5, l32 = t & 31;
    float ss = 0;
    for (int d = l32; d < D_EMB; d += 32) { float v = clip[r][d]; ss += v * v; }
#pragma unroll
    for (int off = 16; off; off >>= 1) ss += __shfl_xor(ss, off);
    if (l32 == 0) norms[r] = sqrtf(ss) + 1e-6f;
  }
  __syncthreads();
  {
    int p = t >> 2, sub = t & 3;
    int i = p >> 3, j = p & 7;
    float s = 0;
    for (int d = sub; d < D_EMB; d += 4) s += clip[i][d] * clip[j][d];
    s += __shfl_xor(s, 1);
    s += __shfl_xor(s, 2);
    if (sub == 0) sc[i][j] = s / (norms[i] * norms[j]);
  }
  __syncthreads();
  const float inv_tls = 1.f / (__expf(tau_lp[0]) * SQRT_D);
  if (t < 64) {
    int i = t >> 3, j = t & 7;
    float v = sc[i][j] * inv_tls;
    float mx = v;
#pragma unroll
    for (int off = 1; off < 8; off <<= 1) mx = fmaxf(mx, __shfl_xor(mx, off));
    float e = __expf(v - mx);
    float s = e;
#pragma unroll
    for (int off = 1; off < 8; off <<= 1) s += __shfl_xor(s, off);
    sc[i][j] = e / s;
  }
  __syncthreads();
  {
    int r = t >> 5, l32 = t & 31;
    float w[8];
#pragma unroll
    for (int j = 0; j < 8; ++j) w[j] = sc[r][j];
    const float invn_nf = 1.f / norms[r];
    if (l32 == 0) invr[c * 8 + r] = invn_nf;
    float accv[36];
    float rs = 0;
#pragma unroll
    for (int kk = 0; kk < 36; ++kk) {
      int d = l32 + kk * 32;
      float a = 0;
#pragma unroll
      for (int j = 0; j < 8; ++j) a += w[j] * clip[j][d];
      accv[kk] = a;
      rs += a * a;
      nf[(size_t)(c * 8 + r) * D_EMB + d] = f2bf(clip[r][d] * invn_nf);
    }
#pragma unroll
    for (int off = 16; off; off >>= 1) rs += __shfl_xor(rs, off);
    if (l32 == 0) nrm2[r] = rs;
    __syncthreads();
    float invn = 1.f / sqrtf(nrm2[r]);
#pragma unroll
    for (int kk = 0; kk < 36; ++kk) {
      int d = l32 + kk * 32;
      loc_n[(size_t)(c * 8 + r) * D_EMB + d] = f2bf(accv[kk] * invn);
    }
  }
}

// ---- scoreA: d0 = te.nf, d1 = te.loc via MFMA; store P1 = .9d0+.05d1, A0 = d0*rn, u = bf16(A0) ----
__global__ __launch_bounds__(256) void k_scoreA(const u16* __restrict__ te_n,
                                                const u16* __restrict__ nf,
                                                const u16* __restrict__ loc_n,
                                                const float* __restrict__ invr,
                                                float* __restrict__ P1,
                                                float* __restrict__ A0,
                                                u16* __restrict__ ubf) {
  const int tid = threadIdx.x;
  const int lane = tid & 63;
  const int wave = tid >> 6;
  const int f0 = blockIdx.x * 16;
  const int fr = lane & 15;
  const int k8 = (lane >> 4) * 8;
  const int kbase = wave * 288;
  f32x4 a0 = {}, a1 = {};
  const u16* teP = te_n + fr * D_EMB + kbase + k8;
  const u16* nfP = nf + (size_t)(f0 + fr) * D_EMB + kbase + k8;
  const u16* lcP = loc_n + (size_t)(f0 + fr) * D_EMB + kbase + k8;
#pragma unroll
  for (int kc = 0; kc < 9; ++kc) {
    bf16x8 aTe = *(const bf16x8*)(teP + kc * 32);
    bf16x8 bNf = *(const bf16x8*)(nfP + kc * 32);
    bf16x8 bLc = *(const bf16x8*)(lcP + kc * 32);
    a0 = __builtin_amdgcn_mfma_f32_16x16x32_bf16(aTe, bNf, a0, 0, 0, 0);
    a1 = __builtin_amdgcn_mfma_f32_16x16x32_bf16(aTe, bLc, a1, 0, 0, 0);
  }
  __shared__ float red[2][4][256];
#pragma unroll
  for (int r = 0; r < 4; ++r) {
    red[0][wave][lane * 4 + r] = a0[r];
    red[1][wave][lane * 4 + r] = a1[r];
  }
  __syncthreads();
  if (wave == 0) {
    const int f = f0 + fr;
    const float rn = 1.f / invr[f];
#pragma unroll
    for (int r = 0; r < 4; ++r) {
      int li = lane * 4 + r;
      float d0 = red[0][0][li] + red[0][1][li] + red[0][2][li] + red[0][3][li];
      float d1 = red[1][0][li] + red[1][1][li] + red[1][2][li] + red[1][3][li];
      int q = (lane >> 4) * 4 + r;
      P1[(size_t)q * NFR + f] = 0.9f * d0 + 0.05f * d1;
      float a = d0 * rn;
      A0[(size_t)q * NFR + f] = a;
      ubf[(size_t)q * NFR + f] = f2bf(a);
    }
  }
}

// ---- tg partials: tgpart[p][q][d] = (nfT . u^T) split-K; p = z*4+wave ----
__global__ __launch_bounds__(256) void k_tg(const u16* __restrict__ nfT,
                                            const u16* __restrict__ ubf,
                                            float* __restrict__ tgpart) {
  const int tid = threadIdx.x;
  const int lane = tid & 63;
  const int wave = tid >> 6;
  const int d0 = blockIdx.x * 128;
  const int kb = blockIdx.y * 512 + wave * 128;
  const int fr = lane & 15;
  const int k8 = (lane >> 4) * 8;
  f32x4 acc[8] = {};
#pragma unroll
  for (int ks = 0; ks < 4; ++ks) {
    int kk = kb + ks * 32;
    bf16x8 b = *(const bf16x8*)&ubf[(size_t)fr * NFR + kk + k8];  // u[q=fr][k..]
#pragma unroll
    for (int m = 0; m < 8; ++m) {
      bf16x8 a = *(const bf16x8*)&nfT[(size_t)(d0 + m * 16 + fr) * NFR + kk + k8];
      acc[m] = __builtin_amdgcn_mfma_f32_16x16x32_bf16(a, b, acc[m], 0, 0, 0);
    }
  }
  float* dst = tgpart + (size_t)(blockIdx.y * 4 + wave) * 16 * D_EMB;
  const int q = fr;  // C col = lane&15 = query
#pragma unroll
  for (int m = 0; m < 8; ++m) {
#pragma unroll
    for (int r = 0; r < 4; ++r) {
      int d = d0 + m * 16 + (lane >> 4) * 4 + r;
      dst[(size_t)q * D_EMB + d] = acc[m][r];
    }
  }
}

// ---- reduce 32 tg partials -> tg bf16 [16][1152]; block 72 computes tec[17] ----
__global__ __launch_bounds__(256) void k_tgred(const float* __restrict__ tgpart,
                                               const u16* __restrict__ te_n,
                                               const float* __restrict__ colsum,
                                               u16* __restrict__ tg,
                                               float* __restrict__ tec) {
  const int t = threadIdx.x;
  if (blockIdx.x < 72) {
    const int idx = blockIdx.x * 256 + t;  // < 18432
    float s = 0.f;
#pragma unroll
    for (int p = 0; p < 32; ++p) s += tgpart[(size_t)p * 18432 + idx];
    tg[idx] = f2bf(s);
  } else {
    if (t < 136) {
      const int v = t >> 3, s8 = t & 7;
      float s = 0.f;
      for (int i = s8; i < D_EMB; i += 8) {
        float a = (v < 16) ? bf2f(te_n[v * D_EMB + i]) : colsum[i];
        s += a * colsum[i];
      }
      s += __shfl_xor(s, 1);
      s += __shfl_xor(s, 2);
      s += __shfl_xor(s, 4);
      if (s8 == 0) tec[v] = s;
    }
  }
}

// ---- scoreB: dtg = tg.nf via MFMA; fuse with P1/A0/tec; max over q -> logits ----
__global__ __launch_bounds__(256) void k_scoreB(const u16* __restrict__ tg,
                                                const u16* __restrict__ nf,
                                                const float* __restrict__ P1,
                                                const float* __restrict__ A0,
                                                const float* __restrict__ tec,
                                                float* __restrict__ logits,
                                                const float* __restrict__ tau_gp,
                                                const float* __restrict__ lsp,
                                                const float* __restrict__ lbp) {
  const int tid = threadIdx.x;
  const int lane = tid & 63;
  const int wave = tid >> 6;
  const int f0 = blockIdx.x * 16;
  const int fr = lane & 15;
  const int k8 = (lane >> 4) * 8;
  const int kbase = wave * 288;
  f32x4 a2 = {};
  const u16* tgP = tg + fr * D_EMB + kbase + k8;
  const u16* nfP = nf + (size_t)(f0 + fr) * D_EMB + kbase + k8;
#pragma unroll
  for (int kc = 0; kc < 9; ++kc) {
    bf16x8 aTg = *(const bf16x8*)(tgP + kc * 32);
    bf16x8 bNf = *(const bf16x8*)(nfP + kc * 32);
    a2 = __builtin_amdgcn_mfma_f32_16x16x32_bf16(aTg, bNf, a2, 0, 0, 0);
  }
  __shared__ float red[4][256];
#pragma unroll
  for (int r = 0; r < 4; ++r) red[wave][lane * 4 + r] = a2[r];
  __syncthreads();
  if (wave == 0) {
    const float inv = 1.f / (__expf(tau_gp[0]) * SQRT_D);
    const float delta = inv * inv * (0.5f + inv * (1.f / 6.f) + inv * inv * (1.f / 24.f));
    const float rsq = rsqrtf(tec[16]);
    const float els = __expf(lsp[0]);
    const float bias = lbp[0];
    const int f = f0 + fr;
    float mx = -1e30f;
#pragma unroll
    for (int r = 0; r < 4; ++r) {
      int li = lane * 4 + r;
      float dtg = red[0][li] + red[1][li] + red[2][li] + red[3][li];
      int q = (lane >> 4) * 4 + r;
      float glob = (tec[q] + inv * dtg + delta * A0[(size_t)q * NFR + f]) * rsq;
      float fused = els * (P1[(size_t)q * NFR + f] + 0.05f * glob) + bias;
      mx = fmaxf(mx, fused);
    }
    mx = fmaxf(mx, __shfl_xor(mx, 16));
    mx = fmaxf(mx, __shfl_xor(mx, 32));
    if (lane < 16) logits[f0 + lane] = mx;
  }
}

// ---------------- softmax-pool per clip + loss ----------------
__global__ __launch_bounds__(512) void k_final(const float* __restrict__ logits,
                                               const float* __restrict__ labels,
                                               float* __restrict__ out) {
  const int t = threadIdx.x;
  float x[8];
  float m = -1e30f;
#pragma unroll
  for (int j = 0; j < 8; ++j) { x[j] = logits[t * 8 + j]; m = fmaxf(m, x[j]); }
  float se = 0, swx = 0;
#pragma unroll
  for (int j = 0; j < 8; ++j) { float e = __expf(x[j] - m); se += e; swx += e * x[j]; }
  float pooled = swx / se;
  out[1 + t] = pooled;
  float lab = labels[t * 8];
  __shared__ float red[8];
  float v = lab;
#pragma unroll
  for (int off = 32; off; off >>= 1) v += __shfl_down(v, off);
  if ((t & 63) == 0) red[t >> 6] = v;
  __syncthreads();
  float total = 0;
#pragma unroll
  for (int w = 0; w < 8; ++w) total += red[w];
  float mean = total * (1.f / 512.f);
  float wgt = pooled * (lab - mean);
  float lsg = (wgt >= 0.f) ? -log1pf(__expf(-wgt)) : (wgt - log1pf(__expf(wgt)));
  __syncthreads();
  float v2 = lsg;
#pragma unroll
  for (int off = 32; off; off >>= 1) v2 += __shfl_down(v2, off);
  if ((t & 63) == 0) red[t >> 6] = v2;
  __syncthreads();
  if (t == 0) {
    float tl = 0;
#pragma unroll
    for (int w = 0; w < 8; ++w) tl += red[w];
    out[0] = -tl;
  }
}

extern "C" void kernel_launch(void* const* d_in, const int* in_sizes, int n_in,
                              void* d_out, int out_size, void* d_ws, size_t ws_size,
                              hipStream_t stream) {
  const float* fe = (const float*)d_in[0];
  const float* text = (const float*)d_in[1];
  const float* labels = (const float*)d_in[2];
  const float* tau_lp = (const float*)d_in[3];
  const float* tau_gp = (const float*)d_in[4];
  const float* lsp = (const float*)d_in[5];
  const float* lbp = (const float*)d_in[6];
  float* out = (float*)d_out;
  char* ws = (char*)d_ws;

  // ws layout (bytes), 256-aligned, total ~32 MB:
  u16* nf = (u16*)(ws + 0);                 // 4096x1152 bf16
  u16* nfT = (u16*)(ws + 9437184);          // 1152x4096 bf16
  u16* loc_n = (u16*)(ws + 18874368);       // 4096x1152 bf16
  u16* te_n = (u16*)(ws + 28311552);        // 16x1152 bf16
  float* invr = (float*)(ws + 28348416);    // 4096 f32
  float* colsum = (float*)(ws + 28364800);  // 1152 f32
  float* kpart = (float*)(ws + 28369408);   // 128x1152 f32
  float* logits = (float*)(ws + 28959232);  // 4096 f32
  float* tec = (float*)(ws + 28975616);     // 17 f32
  float* P1 = (float*)(ws + 28975872);      // 16x4096 f32
  float* A0 = (float*)(ws + 29238016);      // 16x4096 f32
  u16* ubf = (u16*)(ws + 29500160);         // 16x4096 bf16
  float* tgpart = (float*)(ws + 29631232);  // 32x16x1152 f32
  u16* tg = (u16*)(ws + 31990528);          // 16x1152 bf16

  hipLaunchKernelGGL(k_local, dim3(528), dim3(256), 0, stream, fe, text, loc_n, nf, te_n, invr,
                     tau_lp);
  hipLaunchKernelGGL(k_transpose_colsum, dim3(128, 36), dim3(32, 8), 0, stream, fe, invr, nfT,
                     kpart);
  hipLaunchKernelGGL(k_colsum_reduce, dim3(9), dim3(128), 0, stream, kpart, colsum);
  hipLaunchKernelGGL(k_scoreA, dim3(256), dim3(256), 0, stream, te_n, nf, loc_n, invr, P1, A0,
                     ubf);
  hipLaunchKernelGGL(k_tg, dim3(9, 8), dim3(256), 0, stream, nfT, ubf, tgpart);
  hipLaunchKernelGGL(k_tgred, dim3(73), dim3(256), 0, stream, tgpart, te_n, colsum, tg, tec);
  hipLaunchKernelGGL(k_scoreB, dim3(256), dim3(256), 0, stream, tg, nf, P1, A0, tec, logits,
                     tau_gp, lsp, lbp);
  hipLaunchKernelGGL(k_final, dim3(1), dim3(512), 0, stream, logits, labels, out);
}